// Round 13
// baseline (492.507 us; speedup 1.0000x reference)
//
#include <hip/hip_runtime.h>
#include <hip/hip_bf16.h>
#include <cmath>

typedef __attribute__((ext_vector_type(8))) short s8v;   // 8 bf16 (4 VGPR) MFMA operand / 16B chunk
typedef __attribute__((ext_vector_type(4))) float f4v;   // MFMA accumulator

__device__ __forceinline__ f4v mf(s8v a, s8v b, f4v c) {
    return __builtin_amdgcn_mfma_f32_16x16x32_bf16(a, b, c, 0, 0, 0);
}

// RNE float -> bf16 bits (finite inputs only)
__device__ __forceinline__ short bf16_of(float f) {
    unsigned u = __builtin_bit_cast(unsigned, f);
    unsigned r = (u + 0x7FFFu + ((u >> 16) & 1u)) >> 16;
    return (short)r;
}
__device__ __forceinline__ float f_of_bf16(short h) {
    return __builtin_bit_cast(float, ((unsigned)(unsigned short)h) << 16);
}
__device__ __forceinline__ void split2(float v, short& h, short& l) {
    short hh = bf16_of(v);
    h = hh;
    l = bf16_of(v - f_of_bf16(hh));
}

// fast hw sqrt/exp2 (1-ulp; inputs here are normal-range, >= 0)
__device__ __forceinline__ float hw_sqrt(float x) {
    float r;
    asm("v_sqrt_f32 %0, %1" : "=v"(r) : "v"(x));
    return r;
}
__device__ __forceinline__ float hw_exp2(float x) {
    float r;
    asm("v_exp_f32 %0, %1" : "=v"(r) : "v"(x));
    return r;
}

// ---------------------------------------------------------------------------
// Prep 1: z (zr|zi fp32 [4096][1024] each) -> Zhi/Zlo bf16 [4096][2048]
// ---------------------------------------------------------------------------
__global__ __launch_bounds__(256) void prep_z(
    const float* __restrict__ zr, const float* __restrict__ zi,
    short* __restrict__ Zhi, short* __restrict__ Zlo)
{
    int idx = blockIdx.x * 256 + threadIdx.x;        // 0 .. 4096*512-1
    int m = idx >> 9, kq = idx & 511;                // kq = float4 index in 2048-col row
    const float* src = (kq < 256) ? (zr + (size_t)m * 1024 + kq * 4)
                                  : (zi + (size_t)m * 1024 + (kq - 256) * 4);
    float4 v = *reinterpret_cast<const float4*>(src);
    ushort4 hi, lo;
    short h, l;
    split2(v.x, h, l); hi.x = h; lo.x = l;
    split2(v.y, h, l); hi.y = h; lo.y = l;
    split2(v.z, h, l); hi.z = h; lo.z = l;
    split2(v.w, h, l); hi.w = h; lo.w = l;
    *reinterpret_cast<ushort4*>(&Zhi[(size_t)m * 2048 + kq * 4]) = hi;
    *reinterpret_cast<ushort4*>(&Zlo[(size_t)m * 2048 + kq * 4]) = lo;
}

// ---------------------------------------------------------------------------
// Prep 2: q/k/v weights -> packed B [6144][2048] hi/lo bf16 (signs baked).
// ---------------------------------------------------------------------------
__global__ __launch_bounds__(256) void prep_wqkv(
    const float* __restrict__ qwr, const float* __restrict__ qwi,
    const float* __restrict__ kwr, const float* __restrict__ kwi,
    const float* __restrict__ vwr, const float* __restrict__ vwi,
    short* __restrict__ Bqh, short* __restrict__ Bql)
{
    int idx = blockIdx.x * 256 + threadIdx.x;        // 0 .. 6144*512-1
    int n = idx >> 9, kq = idx & 511;
    int k = kq * 4;
    int t = n >> 11, cpart = (n >> 10) & 1, o = n & 1023;
    const float* Wr = (t == 0) ? qwr : (t == 1) ? kwr : vwr;
    const float* Wi = (t == 0) ? qwi : (t == 1) ? kwi : vwi;
    const float* W;
    float sgn;
    int kk;
    if (k < 1024) { W = cpart ? Wi : Wr; sgn = 1.f; kk = k; }
    else          { W = cpart ? Wr : Wi; sgn = cpart ? 1.f : -1.f; kk = k - 1024; }
    float4 v = *reinterpret_cast<const float4*>(W + (size_t)o * 1024 + kk);
    ushort4 hi, lo;
    short h, l;
    split2(sgn * v.x, h, l); hi.x = h; lo.x = l;
    split2(sgn * v.y, h, l); hi.y = h; lo.y = l;
    split2(sgn * v.z, h, l); hi.z = h; lo.z = l;
    split2(sgn * v.w, h, l); hi.w = h; lo.w = l;
    *reinterpret_cast<ushort4*>(&Bqh[(size_t)n * 2048 + k]) = hi;
    *reinterpret_cast<ushort4*>(&Bql[(size_t)n * 2048 + k]) = lo;
}

// ---------------------------------------------------------------------------
// Prep 3: o weights -> packed Bo [2048][2048] bf16 (hi only, signs baked)
// ---------------------------------------------------------------------------
__global__ __launch_bounds__(256) void prep_wo(
    const float* __restrict__ owr, const float* __restrict__ owi,
    short* __restrict__ Boh)
{
    int idx = blockIdx.x * 256 + threadIdx.x;        // 0 .. 2048*512-1
    int n = idx >> 9, kq = idx & 511;
    int k = kq * 4;
    int part = n >> 10, o = n & 1023;
    const float* W;
    float sgn;
    int kk;
    if (k < 1024) { W = part ? owi : owr; sgn = 1.f; kk = k; }
    else          { W = part ? owr : owi; sgn = part ? 1.f : -1.f; kk = k - 1024; }
    float4 v = *reinterpret_cast<const float4*>(W + (size_t)o * 1024 + kk);
    ushort4 hi;
    hi.x = (unsigned short)bf16_of(sgn * v.x);
    hi.y = (unsigned short)bf16_of(sgn * v.y);
    hi.z = (unsigned short)bf16_of(sgn * v.z);
    hi.w = (unsigned short)bf16_of(sgn * v.w);
    *reinterpret_cast<ushort4*>(&Boh[(size_t)n * 2048 + k]) = hi;
}

// ---------------------------------------------------------------------------
// GEMM-Q: [4096 x 2048] x [2048 x 2048] (Q cols only), 3-pass bf16 split.
// ---------------------------------------------------------------------------
__global__ __launch_bounds__(256) void gemm_q(
    const short* __restrict__ Zhi, const short* __restrict__ Zlo,
    const short* __restrict__ Bqh, const short* __restrict__ Bql,
    short* __restrict__ QKhi, short* __restrict__ QKlo)
{
    __shared__ __align__(16) short Ah[128][40], Al[128][40], Bh[128][40], Bl[128][40];
    const int tid = threadIdx.x;
    const int lane = tid & 63, wid = tid >> 6;
    const int c = lane & 15, g = lane >> 4;
    const int wr = wid >> 1, wc = wid & 1;
    const int nt = blockIdx.x, mt = blockIdx.y;
    const int m0 = mt * 128, n0 = nt * 128;

    const f4v zero4 = {0.f, 0.f, 0.f, 0.f};
    f4v acc[4][4];
#pragma unroll
    for (int mi = 0; mi < 4; ++mi)
#pragma unroll
        for (int ni = 0; ni < 4; ++ni) acc[mi][ni] = zero4;

    const int r2 = tid >> 2;            // 0..63
    const int koff = (tid & 3) * 8;     // 0,8,16,24

    for (int kt = 0; kt < 64; ++kt) {
        const int k0 = kt * 32;
        __syncthreads();
#pragma unroll
        for (int half = 0; half < 2; ++half) {
            int row = half * 64 + r2;
            size_t ga = (size_t)(m0 + row) * 2048 + k0 + koff;
            size_t gb = (size_t)(n0 + row) * 2048 + k0 + koff;
            *reinterpret_cast<s8v*>(&Ah[row][koff]) = *reinterpret_cast<const s8v*>(&Zhi[ga]);
            *reinterpret_cast<s8v*>(&Al[row][koff]) = *reinterpret_cast<const s8v*>(&Zlo[ga]);
            *reinterpret_cast<s8v*>(&Bh[row][koff]) = *reinterpret_cast<const s8v*>(&Bqh[gb]);
            *reinterpret_cast<s8v*>(&Bl[row][koff]) = *reinterpret_cast<const s8v*>(&Bql[gb]);
        }
        __syncthreads();

        s8v ah[4], alo[4], bh[4], blo[4];
#pragma unroll
        for (int i = 0; i < 4; ++i) {
            ah[i]  = *reinterpret_cast<const s8v*>(&Ah[wr * 64 + i * 16 + c][8 * g]);
            alo[i] = *reinterpret_cast<const s8v*>(&Al[wr * 64 + i * 16 + c][8 * g]);
            bh[i]  = *reinterpret_cast<const s8v*>(&Bh[wc * 64 + i * 16 + c][8 * g]);
            blo[i] = *reinterpret_cast<const s8v*>(&Bl[wc * 64 + i * 16 + c][8 * g]);
        }
        __builtin_amdgcn_s_setprio(1);
#pragma unroll
        for (int mi = 0; mi < 4; ++mi)
#pragma unroll
            for (int ni = 0; ni < 4; ++ni) {
                acc[mi][ni] = mf(ah[mi], bh[ni], acc[mi][ni]);
                acc[mi][ni] = mf(ah[mi], blo[ni], acc[mi][ni]);
                acc[mi][ni] = mf(alo[mi], bh[ni], acc[mi][ni]);
            }
        __builtin_amdgcn_s_setprio(0);
    }

    // epilogue: cols all < 2048 -> Q hi + lo
#pragma unroll
    for (int mi = 0; mi < 4; ++mi) {
#pragma unroll
        for (int ni = 0; ni < 4; ++ni) {
            int col = n0 + wc * 64 + ni * 16 + c;
            int rbase = m0 + wr * 64 + mi * 16 + 4 * g;
#pragma unroll
            for (int j = 0; j < 4; ++j) {
                short h, l;
                split2(acc[mi][ni][j], h, l);
                QKhi[(size_t)(rbase + j) * 4096 + col] = h;
                QKlo[(size_t)(rbase + j) * 2048 + col] = l;
            }
        }
    }
}

// ---------------------------------------------------------------------------
// GEMM-KV: [4096 x 2048] x [2048 x 4096] (K,V cols), single bf16 pass.
// ---------------------------------------------------------------------------
__global__ __launch_bounds__(256) void gemm_kv(
    const short* __restrict__ Zhi,
    const short* __restrict__ Bqh,
    short* __restrict__ QKhi,
    short* __restrict__ Vtr, short* __restrict__ Vti)
{
    __shared__ __align__(16) short Ah[128][40], Bh[128][40];
    const int tid = threadIdx.x;
    const int lane = tid & 63, wid = tid >> 6;
    const int c = lane & 15, g = lane >> 4;
    const int wr = wid >> 1, wc = wid & 1;
    const int nt = blockIdx.x, mt = blockIdx.y;
    const int m0 = mt * 128, n0 = 2048 + nt * 128;

    const f4v zero4 = {0.f, 0.f, 0.f, 0.f};
    f4v acc[4][4];
#pragma unroll
    for (int mi = 0; mi < 4; ++mi)
#pragma unroll
        for (int ni = 0; ni < 4; ++ni) acc[mi][ni] = zero4;

    const int r2 = tid >> 2;            // 0..63
    const int koff = (tid & 3) * 8;     // 0,8,16,24

    for (int kt = 0; kt < 64; ++kt) {
        const int k0 = kt * 32;
        __syncthreads();
#pragma unroll
        for (int half = 0; half < 2; ++half) {
            int row = half * 64 + r2;
            size_t ga = (size_t)(m0 + row) * 2048 + k0 + koff;
            size_t gb = (size_t)(n0 + row) * 2048 + k0 + koff;
            *reinterpret_cast<s8v*>(&Ah[row][koff]) = *reinterpret_cast<const s8v*>(&Zhi[ga]);
            *reinterpret_cast<s8v*>(&Bh[row][koff]) = *reinterpret_cast<const s8v*>(&Bqh[gb]);
        }
        __syncthreads();

        s8v ah[4], bh[4];
#pragma unroll
        for (int i = 0; i < 4; ++i) {
            ah[i] = *reinterpret_cast<const s8v*>(&Ah[wr * 64 + i * 16 + c][8 * g]);
            bh[i] = *reinterpret_cast<const s8v*>(&Bh[wc * 64 + i * 16 + c][8 * g]);
        }
        __builtin_amdgcn_s_setprio(1);
#pragma unroll
        for (int mi = 0; mi < 4; ++mi)
#pragma unroll
            for (int ni = 0; ni < 4; ++ni)
                acc[mi][ni] = mf(ah[mi], bh[ni], acc[mi][ni]);
        __builtin_amdgcn_s_setprio(0);
    }

    // epilogue: K cols -> QKhi; V cols -> V^T
#pragma unroll
    for (int mi = 0; mi < 4; ++mi) {
#pragma unroll
        for (int ni = 0; ni < 4; ++ni) {
            int col = n0 + wc * 64 + ni * 16 + c;
            int rbase = m0 + wr * 64 + mi * 16 + 4 * g;
            if (col < 4096) {
#pragma unroll
                for (int j = 0; j < 4; ++j)
                    QKhi[(size_t)(rbase + j) * 4096 + col] = bf16_of(acc[mi][ni][j]);
            } else {
                int cc = col - 4096;
                int part = cc >> 10, o = cc & 1023;
                int hh = o >> 6, d = o & 63;
                int bb = rbase >> 11, s = rbase & 2047;
                short* vt = part ? Vti : Vtr;
                ushort4 pk;
                pk.x = (unsigned short)bf16_of(acc[mi][ni][0]);
                pk.y = (unsigned short)bf16_of(acc[mi][ni][1]);
                pk.z = (unsigned short)bf16_of(acc[mi][ni][2]);
                pk.w = (unsigned short)bf16_of(acc[mi][ni][3]);
                *reinterpret_cast<ushort4*>(&vt[((size_t)(bb * 16 + hh) * 64 + d) * 2048 + s]) = pk;
            }
        }
    }
}

// ---------------------------------------------------------------------------
// Fused flash attention, no split-K (1024 blocks = exactly 4/CU, single
// residency shift; split-K's extra waves no longer needed now the kernel is
// pipe-bound). K AND V staged in LDS once per block (round-11: 4 global
// instrs/wave/kt). Raw v_sqrt/v_exp score math (round-12). Swapped QK^T,
// flattened softmax (scores in [0,44.2], no max-sub), in-kernel normalize,
// direct bf16 aout write. KVBLK=32 double-buffered.
// ---------------------------------------------------------------------------
__global__ __launch_bounds__(256) void attn_fused(
    const short* __restrict__ QKhi, const short* __restrict__ QKlo,
    const short* __restrict__ Vtr, const short* __restrict__ Vti,
    short* __restrict__ aout)
{
    __shared__ short kbuf[2][32][128];                 // 16 KB: row=key, [kr|ki], XOR slots
    __shared__ short vbuf[2][64][64];                  // 16 KB: row=d, [vr 32k|vi 32k], XOR slots
    __shared__ __align__(16) short p_lds[4][16][40];   // 5 KB per-wave P tiles
    const int tid = threadIdx.x, lane = tid & 63, wid = tid >> 6;
    const int c = lane & 15, g = lane >> 4;

    // XCD swizzle: all 32 q-tiles of one (b,h) on one XCD.
    const int L = blockIdx.x;                    // 0..1023
    const int idx = L >> 3;                      // 0..127
    const int p = (L & 7) + ((idx >> 5) << 3);   // (b,h) pair 0..31
    const int qt = idx & 31;
    const int h = p & 15, b = p >> 4;

    const int q0 = qt * 64 + wid * 16;
    const int mq = b * 2048 + q0 + c;

    s8v qrh[2], qrl[2], qih[2], qil[2], nqrh[2], nqrl[2];
#pragma unroll
    for (int ks = 0; ks < 2; ++ks) {
        int colr = h * 64 + ks * 32 + 8 * g;
        qrh[ks] = *reinterpret_cast<const s8v*>(&QKhi[(size_t)mq * 4096 + colr]);
        qrl[ks] = *reinterpret_cast<const s8v*>(&QKlo[(size_t)mq * 2048 + colr]);
        qih[ks] = *reinterpret_cast<const s8v*>(&QKhi[(size_t)mq * 4096 + 1024 + colr]);
        qil[ks] = *reinterpret_cast<const s8v*>(&QKlo[(size_t)mq * 2048 + 1024 + colr]);
        nqrh[ks] = qrh[ks] ^ (short)0x8000;
        nqrl[ks] = qrl[ks] ^ (short)0x8000;
    }

    // K staging: LDS row r holds key; physical 16B slot s holds logical
    // u = s^(r&7); u 0..7 = kr d[0..63], 8..15 = ki.
    const int srow = tid >> 4;                 // 0..15
    const int sslot = tid & 15;
    const int kslot_u = sslot ^ (srow & 7);
    const int gcolK = 2048 + (kslot_u >> 3) * 1024 + h * 64 + (kslot_u & 7) * 8;
    const short* gK = QKhi + (size_t)(b * 2048) * 4096 + gcolK;

    // V staging: vbuf row = d (0..63); physical slot s (0..7) holds logical
    // u = s^(d&7); u 0..3 = vr keys [8u..8u+7], u 4..7 = vi keys [8(u-4)..].
    const int vlr = lane >> 3;                  // local row 0..7
    const int vs = lane & 7;                    // physical slot
    const short* gV[2];
#pragma unroll
    for (int i = 0; i < 2; ++i) {
        int d = wid * 16 + i * 8 + vlr;
        int u = vs ^ (d & 7);
        const short* base = (u < 4) ? Vtr : Vti;
        gV[i] = base + (size_t)((b * 16 + h) * 64 + d) * 2048 + (u & 3) * 8;
    }

    const f4v zero4 = {0.f, 0.f, 0.f, 0.f};
    f4v aor[4], aoi[4];
#pragma unroll
    for (int dt = 0; dt < 4; ++dt) { aor[dt] = zero4; aoi[dt] = zero4; }
    float lrun = 0.f;        // all of this lane's scores belong to q = q0 + c

    // exp(s*0.125) == exp2(s*0.125*log2e)
    const float ESC = 0.125f * 1.44269504f;

    // prologue: stage tile 0 (K + V)
#pragma unroll
    for (int i = 0; i < 2; ++i) {
        __builtin_amdgcn_global_load_lds(
            gK + (size_t)(i * 16 + srow) * 4096,
            &kbuf[0][i * 16 + wid * 4][0], 16, 0, 0);
        __builtin_amdgcn_global_load_lds(
            gV[i],
            &vbuf[0][wid * 16 + i * 8][0], 16, 0, 0);
    }
    __syncthreads();

    for (int kt = 0; kt < 64; ++kt) {
        const int buf = kt & 1;
        if (kt + 1 < 64) {
            const int ko = (kt + 1) * 32;
#pragma unroll
            for (int i = 0; i < 2; ++i) {
                __builtin_amdgcn_global_load_lds(
                    gK + (size_t)(ko + i * 16 + srow) * 4096,
                    &kbuf[buf ^ 1][i * 16 + wid * 4][0], 16, 0, 0);
                __builtin_amdgcn_global_load_lds(
                    gV[i] + ko,
                    &vbuf[buf ^ 1][wid * 16 + i * 8][0], 16, 0, 0);
            }
        }

#pragma unroll
        for (int kn = 0; kn < 2; ++kn) {
            f4v sr = zero4, si = zero4;
            const int row = kn * 16 + c;
#pragma unroll
            for (int ks = 0; ks < 2; ++ks) {
                const int sl = (((ks * 4 + g) ^ (c & 7))) * 8;
                s8v krh = *reinterpret_cast<const s8v*>(&kbuf[buf][row][sl]);
                s8v kih = *reinterpret_cast<const s8v*>(&kbuf[buf][row][sl + 64]);
                // swapped operands: lane(c,g) reg j = S[q=c][k=kn*16+4g+j]
                sr = mf(krh, qrh[ks], sr); sr = mf(krh, qrl[ks], sr);
                sr = mf(kih, qih[ks], sr); sr = mf(kih, qil[ks], sr);
                si = mf(krh, qih[ks], si); si = mf(krh, qil[ks], si);
                si = mf(kih, nqrh[ks], si); si = mf(kih, nqrl[ks], si);
            }
            float pv0, pv1, pv2, pv3;
            {
                float a, e;
                a = sr[0]; e = si[0];
                pv0 = hw_exp2(hw_sqrt(__builtin_fmaf(e, e, a * a)) * ESC);
                a = sr[1]; e = si[1];
                pv1 = hw_exp2(hw_sqrt(__builtin_fmaf(e, e, a * a)) * ESC);
                a = sr[2]; e = si[2];
                pv2 = hw_exp2(hw_sqrt(__builtin_fmaf(e, e, a * a)) * ESC);
                a = sr[3]; e = si[3];
                pv3 = hw_exp2(hw_sqrt(__builtin_fmaf(e, e, a * a)) * ESC);
            }
            lrun += (pv0 + pv1) + (pv2 + pv3);
            unsigned lo32, hi32;
            asm("v_cvt_pk_bf16_f32 %0, %1, %2" : "=v"(lo32) : "v"(pv0), "v"(pv1));
            asm("v_cvt_pk_bf16_f32 %0, %1, %2" : "=v"(hi32) : "v"(pv2), "v"(pv3));
            uint2 pk2; pk2.x = lo32; pk2.y = hi32;
            *reinterpret_cast<uint2*>(&p_lds[wid][c][kn * 16 + 4 * g]) = pk2;
        }

        // PV: P is [16q x 32k] per wave; V from shared vbuf (swizzled read)
        s8v pa = *reinterpret_cast<const s8v*>(&p_lds[wid][c][8 * g]);
#pragma unroll
        for (int dt = 0; dt < 4; ++dt) {
            const int d = dt * 16 + c;
            const int sr_ = (g ^ (d & 7)) * 8;          // vr logical slot g
            const int si_ = ((4 + g) ^ (d & 7)) * 8;    // vi logical slot 4+g
            s8v vr = *reinterpret_cast<const s8v*>(&vbuf[buf][d][sr_]);
            s8v vi = *reinterpret_cast<const s8v*>(&vbuf[buf][d][si_]);
            aor[dt] = mf(pa, vr, aor[dt]);
            aoi[dt] = mf(pa, vi, aoi[dt]);
        }
        __syncthreads();   // kbuf/vbuf[buf] free; next tile staged
    }

    // row-sum over the 4 g-groups (lanes c, c+16, c+32, c+48 share q = q0+c)
    float rt = lrun;
    rt += __shfl_xor(rt, 16);
    rt += __shfl_xor(rt, 32);
    // O rows are q = q0 + 4g + j -> fetch l for those rows
    f4v ilv;
#pragma unroll
    for (int j = 0; j < 4; ++j) ilv[j] = 1.f / __shfl(rt, 4 * g + j);

#pragma unroll
    for (int dt = 0; dt < 4; ++dt) {
        f4v orv = aor[dt] * ilv, oiv = aoi[dt] * ilv;
#pragma unroll
        for (int j = 0; j < 4; ++j) {
            int row = b * 2048 + q0 + 4 * g + j;
            aout[(size_t)row * 2048 + h * 64 + dt * 16 + c] = bf16_of(orv[j]);
            aout[(size_t)row * 2048 + 1024 + h * 64 + dt * 16 + c] = bf16_of(oiv[j]);
        }
    }
}

// ---------------------------------------------------------------------------
// GEMM2: attn_out [4096 x 2048] x packed o_w bf16 [2048 x 2048] -> yr|yi fp32
// ---------------------------------------------------------------------------
__global__ __launch_bounds__(256) void gemm_out(
    const short* __restrict__ A,
    const short* __restrict__ Boh,
    float* __restrict__ out)
{
    __shared__ __align__(16) short Ah[128][40], Bh[128][40];
    const int tid = threadIdx.x;
    const int lane = tid & 63, wid = tid >> 6;
    const int c = lane & 15, g = lane >> 4;
    const int wr = wid >> 1, wc = wid & 1;
    const int nt = blockIdx.x, mt = blockIdx.y;
    const int m0 = mt * 128, n0 = nt * 128;

    const f4v zero4 = {0.f, 0.f, 0.f, 0.f};
    f4v acc[4][4];
#pragma unroll
    for (int mi = 0; mi < 4; ++mi)
#pragma unroll
        for (int ni = 0; ni < 4; ++ni) acc[mi][ni] = zero4;

    const int r2 = tid >> 2;
    const int koff = (tid & 3) * 8;

    for (int kt = 0; kt < 64; ++kt) {
        const int k0 = kt * 32;
        __syncthreads();
#pragma unroll
        for (int half = 0; half < 2; ++half) {
            int row = half * 64 + r2;
            *reinterpret_cast<s8v*>(&Ah[row][koff]) =
                *reinterpret_cast<const s8v*>(&A[(size_t)(m0 + row) * 2048 + k0 + koff]);
            *reinterpret_cast<s8v*>(&Bh[row][koff]) =
                *reinterpret_cast<const s8v*>(&Boh[(size_t)(n0 + row) * 2048 + k0 + koff]);
        }
        __syncthreads();

        s8v af[4], bfr[4];
#pragma unroll
        for (int i = 0; i < 4; ++i) {
            af[i]  = *reinterpret_cast<const s8v*>(&Ah[wr * 64 + i * 16 + c][8 * g]);
            bfr[i] = *reinterpret_cast<const s8v*>(&Bh[wc * 64 + i * 16 + c][8 * g]);
        }
        __builtin_amdgcn_s_setprio(1);
#pragma unroll
        for (int mi = 0; mi < 4; ++mi)
#pragma unroll
            for (int ni = 0; ni < 4; ++ni)
                acc[mi][ni] = mf(af[mi], bfr[ni], acc[mi][ni]);
        __builtin_amdgcn_s_setprio(0);
    }

#pragma unroll
    for (int mi = 0; mi < 4; ++mi)
#pragma unroll
        for (int ni = 0; ni < 4; ++ni) {
            int col = n0 + wc * 64 + ni * 16 + c;
#pragma unroll
            for (int j = 0; j < 4; ++j) {
                int row = m0 + wr * 64 + mi * 16 + 4 * g + j;
                float v = acc[mi][ni][j];
                if (col < 1024) out[(size_t)row * 1024 + col] = v;
                else out[4194304 + (size_t)row * 1024 + (col - 1024)] = v;
            }
        }
}

extern "C" void kernel_launch(void* const* d_in, const int* in_sizes, int n_in,
                              void* d_out, int out_size, void* d_ws, size_t ws_size,
                              hipStream_t stream) {
    const float* zr  = (const float*)d_in[0];
    const float* zi  = (const float*)d_in[1];
    const float* qwr = (const float*)d_in[2];
    const float* qwi = (const float*)d_in[3];
    const float* kwr = (const float*)d_in[4];
    const float* kwi = (const float*)d_in[5];
    const float* vwr = (const float*)d_in[6];
    const float* vwi = (const float*)d_in[7];
    const float* owr = (const float*)d_in[8];
    const float* owi = (const float*)d_in[9];

    char* ws = (char*)d_ws;
    short* QKhi = (short*)(ws);                      // 33554432 B
    short* QKlo = (short*)(ws + 33554432);           // 16777216 B (Q cols only)
    short* Vtr  = (short*)(ws + 50331648);           //  8388608 B
    short* Vti  = (short*)(ws + 58720256);           //  8388608 B
    short* aout = (short*)(ws + 67108864);           // 16777216 B
    short* Zhi  = (short*)(ws + 83886080);           // 16777216 B
    short* Zlo  = (short*)(ws + 100663296);          // 16777216 B
    short* Bqh  = (short*)(ws + 117440512);          // 25165824 B
    short* Bql  = (short*)(ws + 142606336);          // 25165824 B
    short* Boh  = (short*)(ws + 167772160);          //  8388608 B  (total 176160768)

    prep_z<<<dim3(8192), 256, 0, stream>>>(zr, zi, Zhi, Zlo);
    prep_wqkv<<<dim3(12288), 256, 0, stream>>>(qwr, qwi, kwr, kwi, vwr, vwi, Bqh, Bql);
    prep_wo<<<dim3(4096), 256, 0, stream>>>(owr, owi, Boh);
    gemm_q<<<dim3(16, 32, 1), 256, 0, stream>>>(Zhi, Zlo, Bqh, Bql, QKhi, QKlo);
    gemm_kv<<<dim3(32, 32, 1), 256, 0, stream>>>(Zhi, Bqh, QKhi, Vtr, Vti);
    attn_fused<<<dim3(1024), 256, 0, stream>>>(QKhi, QKlo, Vtr, Vti, aout);
    gemm_out<<<dim3(16, 32, 1), 256, 0, stream>>>(aout, Boh, (float*)d_out);
}

// Round 14
// 466.038 us; speedup vs baseline: 1.0568x; 1.0568x over previous
//
#include <hip/hip_runtime.h>
#include <hip/hip_bf16.h>
#include <cmath>

typedef __attribute__((ext_vector_type(8))) short s8v;   // 8 bf16 (4 VGPR) MFMA operand / 16B chunk
typedef __attribute__((ext_vector_type(4))) float f4v;   // MFMA accumulator

__device__ __forceinline__ f4v mf(s8v a, s8v b, f4v c) {
    return __builtin_amdgcn_mfma_f32_16x16x32_bf16(a, b, c, 0, 0, 0);
}

// RNE float -> bf16 bits (finite inputs only)
__device__ __forceinline__ short bf16_of(float f) {
    unsigned u = __builtin_bit_cast(unsigned, f);
    unsigned r = (u + 0x7FFFu + ((u >> 16) & 1u)) >> 16;
    return (short)r;
}
__device__ __forceinline__ float f_of_bf16(short h) {
    return __builtin_bit_cast(float, ((unsigned)(unsigned short)h) << 16);
}
__device__ __forceinline__ void split2(float v, short& h, short& l) {
    short hh = bf16_of(v);
    h = hh;
    l = bf16_of(v - f_of_bf16(hh));
}

// fast hw sqrt/exp2 (1-ulp; inputs here are normal-range, >= 0)
__device__ __forceinline__ float hw_sqrt(float x) {
    float r;
    asm("v_sqrt_f32 %0, %1" : "=v"(r) : "v"(x));
    return r;
}
__device__ __forceinline__ float hw_exp2(float x) {
    float r;
    asm("v_exp_f32 %0, %1" : "=v"(r) : "v"(x));
    return r;
}

// ---------------------------------------------------------------------------
// Merged prep: blocks [0,8192) = z -> Zhi/Zlo; [8192,20480) = qkv weights ->
// Bqh/Bql (signs baked); [20480,24576) = o weights -> Boh.
// ---------------------------------------------------------------------------
__global__ __launch_bounds__(256) void prep_all(
    const float* __restrict__ zr, const float* __restrict__ zi,
    const float* __restrict__ qwr, const float* __restrict__ qwi,
    const float* __restrict__ kwr, const float* __restrict__ kwi,
    const float* __restrict__ vwr, const float* __restrict__ vwi,
    const float* __restrict__ owr, const float* __restrict__ owi,
    short* __restrict__ Zhi, short* __restrict__ Zlo,
    short* __restrict__ Bqh, short* __restrict__ Bql,
    short* __restrict__ Boh)
{
    int blk = blockIdx.x;
    if (blk < 8192) {
        int idx = blk * 256 + threadIdx.x;
        int m = idx >> 9, kq = idx & 511;
        const float* src = (kq < 256) ? (zr + (size_t)m * 1024 + kq * 4)
                                      : (zi + (size_t)m * 1024 + (kq - 256) * 4);
        float4 v = *reinterpret_cast<const float4*>(src);
        ushort4 hi, lo;
        short h, l;
        split2(v.x, h, l); hi.x = h; lo.x = l;
        split2(v.y, h, l); hi.y = h; lo.y = l;
        split2(v.z, h, l); hi.z = h; lo.z = l;
        split2(v.w, h, l); hi.w = h; lo.w = l;
        *reinterpret_cast<ushort4*>(&Zhi[(size_t)m * 2048 + kq * 4]) = hi;
        *reinterpret_cast<ushort4*>(&Zlo[(size_t)m * 2048 + kq * 4]) = lo;
    } else if (blk < 20480) {
        int idx = (blk - 8192) * 256 + threadIdx.x;
        int n = idx >> 9, kq = idx & 511;
        int k = kq * 4;
        int t = n >> 11, cpart = (n >> 10) & 1, o = n & 1023;
        const float* Wr = (t == 0) ? qwr : (t == 1) ? kwr : vwr;
        const float* Wi = (t == 0) ? qwi : (t == 1) ? kwi : vwi;
        const float* W;
        float sgn;
        int kk;
        if (k < 1024) { W = cpart ? Wi : Wr; sgn = 1.f; kk = k; }
        else          { W = cpart ? Wr : Wi; sgn = cpart ? 1.f : -1.f; kk = k - 1024; }
        float4 v = *reinterpret_cast<const float4*>(W + (size_t)o * 1024 + kk);
        ushort4 hi, lo;
        short h, l;
        split2(sgn * v.x, h, l); hi.x = h; lo.x = l;
        split2(sgn * v.y, h, l); hi.y = h; lo.y = l;
        split2(sgn * v.z, h, l); hi.z = h; lo.z = l;
        split2(sgn * v.w, h, l); hi.w = h; lo.w = l;
        *reinterpret_cast<ushort4*>(&Bqh[(size_t)n * 2048 + k]) = hi;
        *reinterpret_cast<ushort4*>(&Bql[(size_t)n * 2048 + k]) = lo;
    } else {
        int idx = (blk - 20480) * 256 + threadIdx.x;
        int n = idx >> 9, kq = idx & 511;
        int k = kq * 4;
        int part = n >> 10, o = n & 1023;
        const float* W;
        float sgn;
        int kk;
        if (k < 1024) { W = part ? owi : owr; sgn = 1.f; kk = k; }
        else          { W = part ? owr : owi; sgn = part ? 1.f : -1.f; kk = k - 1024; }
        float4 v = *reinterpret_cast<const float4*>(W + (size_t)o * 1024 + kk);
        ushort4 hi;
        hi.x = (unsigned short)bf16_of(sgn * v.x);
        hi.y = (unsigned short)bf16_of(sgn * v.y);
        hi.z = (unsigned short)bf16_of(sgn * v.z);
        hi.w = (unsigned short)bf16_of(sgn * v.w);
        *reinterpret_cast<ushort4*>(&Boh[(size_t)n * 2048 + k]) = hi;
    }
}

// ---------------------------------------------------------------------------
// GEMM staging via global_load_lds, XOR-swizzled [128][32] tiles (64B rows,
// 4x 16B slots; physical slot = logical ^ ((row>>1)&3)). Write side: lane l
// stages row base+(l>>2), phys slot l&3 -> source chunk (l&3)^((l>>3)&3).
// Read side: (row>>1)&3 == (c>>1)&3 -> per-lane constant col swizzle; banks
// spread 2-way (free). Per-lane global pointers bumped 64B per kt.
// ---------------------------------------------------------------------------

// GEMM-Q: [4096 x 2048] x [2048 x 2048] (Q cols only), 3-pass bf16 split.
__global__ __launch_bounds__(256) void gemm_q(
    const short* __restrict__ Zhi, const short* __restrict__ Zlo,
    const short* __restrict__ Bqh, const short* __restrict__ Bql,
    short* __restrict__ QKhi, short* __restrict__ QKlo)
{
    __shared__ __align__(16) short Ah[128][32], Al[128][32], Bh[128][32], Bl[128][32];
    const int tid = threadIdx.x;
    const int lane = tid & 63, wid = tid >> 6;
    const int c = lane & 15, g = lane >> 4;
    const int wr = wid >> 1, wc = wid & 1;
    const int nt = blockIdx.x, mt = blockIdx.y;
    const int m0 = mt * 128, n0 = nt * 128;

    const f4v zero4 = {0.f, 0.f, 0.f, 0.f};
    f4v acc[4][4];
#pragma unroll
    for (int mi = 0; mi < 4; ++mi)
#pragma unroll
        for (int ni = 0; ni < 4; ++ni) acc[mi][ni] = zero4;

    // staging source pointers
    const int rloc = lane >> 2;                       // 0..15
    const int Lch = (lane & 3) ^ ((lane >> 3) & 3);   // source chunk
    const int arow = m0 + wid * 16 + rloc;
    const int brow = n0 + wid * 16 + rloc;
    const short* gAh0 = Zhi + (size_t)arow * 2048 + Lch * 8;
    const short* gAh1 = gAh0 + (size_t)64 * 2048;
    const short* gAl0 = Zlo + (size_t)arow * 2048 + Lch * 8;
    const short* gAl1 = gAl0 + (size_t)64 * 2048;
    const short* gBh0 = Bqh + (size_t)brow * 2048 + Lch * 8;
    const short* gBh1 = gBh0 + (size_t)64 * 2048;
    const short* gBl0 = Bql + (size_t)brow * 2048 + Lch * 8;
    const short* gBl1 = gBl0 + (size_t)64 * 2048;

    const int cswz = (g ^ ((c >> 1) & 3)) * 8;        // read-side swizzled col

    for (int kt = 0; kt < 64; ++kt) {
        __syncthreads();
        __builtin_amdgcn_global_load_lds(gAh0, &Ah[wid * 16][0], 16, 0, 0);
        __builtin_amdgcn_global_load_lds(gAh1, &Ah[64 + wid * 16][0], 16, 0, 0);
        __builtin_amdgcn_global_load_lds(gAl0, &Al[wid * 16][0], 16, 0, 0);
        __builtin_amdgcn_global_load_lds(gAl1, &Al[64 + wid * 16][0], 16, 0, 0);
        __builtin_amdgcn_global_load_lds(gBh0, &Bh[wid * 16][0], 16, 0, 0);
        __builtin_amdgcn_global_load_lds(gBh1, &Bh[64 + wid * 16][0], 16, 0, 0);
        __builtin_amdgcn_global_load_lds(gBl0, &Bl[wid * 16][0], 16, 0, 0);
        __builtin_amdgcn_global_load_lds(gBl1, &Bl[64 + wid * 16][0], 16, 0, 0);
        gAh0 += 32; gAh1 += 32; gAl0 += 32; gAl1 += 32;
        gBh0 += 32; gBh1 += 32; gBl0 += 32; gBl1 += 32;
        __syncthreads();

        s8v ah[4], alo[4], bh[4], blo[4];
#pragma unroll
        for (int i = 0; i < 4; ++i) {
            ah[i]  = *reinterpret_cast<const s8v*>(&Ah[wr * 64 + i * 16 + c][cswz]);
            alo[i] = *reinterpret_cast<const s8v*>(&Al[wr * 64 + i * 16 + c][cswz]);
            bh[i]  = *reinterpret_cast<const s8v*>(&Bh[wc * 64 + i * 16 + c][cswz]);
            blo[i] = *reinterpret_cast<const s8v*>(&Bl[wc * 64 + i * 16 + c][cswz]);
        }
        __builtin_amdgcn_s_setprio(1);
#pragma unroll
        for (int mi = 0; mi < 4; ++mi)
#pragma unroll
            for (int ni = 0; ni < 4; ++ni) {
                acc[mi][ni] = mf(ah[mi], bh[ni], acc[mi][ni]);
                acc[mi][ni] = mf(ah[mi], blo[ni], acc[mi][ni]);
                acc[mi][ni] = mf(alo[mi], bh[ni], acc[mi][ni]);
            }
        __builtin_amdgcn_s_setprio(0);
    }

    // epilogue: cols all < 2048 -> Q hi + lo
#pragma unroll
    for (int mi = 0; mi < 4; ++mi) {
#pragma unroll
        for (int ni = 0; ni < 4; ++ni) {
            int col = n0 + wc * 64 + ni * 16 + c;
            int rbase = m0 + wr * 64 + mi * 16 + 4 * g;
#pragma unroll
            for (int j = 0; j < 4; ++j) {
                short h, l;
                split2(acc[mi][ni][j], h, l);
                QKhi[(size_t)(rbase + j) * 4096 + col] = h;
                QKlo[(size_t)(rbase + j) * 2048 + col] = l;
            }
        }
    }
}

// GEMM-KV: [4096 x 2048] x [2048 x 4096] (K,V cols), single bf16 pass.
__global__ __launch_bounds__(256) void gemm_kv(
    const short* __restrict__ Zhi,
    const short* __restrict__ Bqh,
    short* __restrict__ QKhi,
    short* __restrict__ Vtr, short* __restrict__ Vti)
{
    __shared__ __align__(16) short Ah[128][32], Bh[128][32];
    const int tid = threadIdx.x;
    const int lane = tid & 63, wid = tid >> 6;
    const int c = lane & 15, g = lane >> 4;
    const int wr = wid >> 1, wc = wid & 1;
    const int nt = blockIdx.x, mt = blockIdx.y;
    const int m0 = mt * 128, n0 = 2048 + nt * 128;

    const f4v zero4 = {0.f, 0.f, 0.f, 0.f};
    f4v acc[4][4];
#pragma unroll
    for (int mi = 0; mi < 4; ++mi)
#pragma unroll
        for (int ni = 0; ni < 4; ++ni) acc[mi][ni] = zero4;

    const int rloc = lane >> 2;
    const int Lch = (lane & 3) ^ ((lane >> 3) & 3);
    const int arow = m0 + wid * 16 + rloc;
    const int brow = n0 + wid * 16 + rloc;
    const short* gA0 = Zhi + (size_t)arow * 2048 + Lch * 8;
    const short* gA1 = gA0 + (size_t)64 * 2048;
    const short* gB0 = Bqh + (size_t)brow * 2048 + Lch * 8;
    const short* gB1 = gB0 + (size_t)64 * 2048;

    const int cswz = (g ^ ((c >> 1) & 3)) * 8;

    for (int kt = 0; kt < 64; ++kt) {
        __syncthreads();
        __builtin_amdgcn_global_load_lds(gA0, &Ah[wid * 16][0], 16, 0, 0);
        __builtin_amdgcn_global_load_lds(gA1, &Ah[64 + wid * 16][0], 16, 0, 0);
        __builtin_amdgcn_global_load_lds(gB0, &Bh[wid * 16][0], 16, 0, 0);
        __builtin_amdgcn_global_load_lds(gB1, &Bh[64 + wid * 16][0], 16, 0, 0);
        gA0 += 32; gA1 += 32; gB0 += 32; gB1 += 32;
        __syncthreads();

        s8v ah[4], bh[4];
#pragma unroll
        for (int i = 0; i < 4; ++i) {
            ah[i] = *reinterpret_cast<const s8v*>(&Ah[wr * 64 + i * 16 + c][cswz]);
            bh[i] = *reinterpret_cast<const s8v*>(&Bh[wc * 64 + i * 16 + c][cswz]);
        }
        __builtin_amdgcn_s_setprio(1);
#pragma unroll
        for (int mi = 0; mi < 4; ++mi)
#pragma unroll
            for (int ni = 0; ni < 4; ++ni)
                acc[mi][ni] = mf(ah[mi], bh[ni], acc[mi][ni]);
        __builtin_amdgcn_s_setprio(0);
    }

    // epilogue: K cols -> QKhi; V cols -> V^T
#pragma unroll
    for (int mi = 0; mi < 4; ++mi) {
#pragma unroll
        for (int ni = 0; ni < 4; ++ni) {
            int col = n0 + wc * 64 + ni * 16 + c;
            int rbase = m0 + wr * 64 + mi * 16 + 4 * g;
            if (col < 4096) {
#pragma unroll
                for (int j = 0; j < 4; ++j)
                    QKhi[(size_t)(rbase + j) * 4096 + col] = bf16_of(acc[mi][ni][j]);
            } else {
                int cc = col - 4096;
                int part = cc >> 10, o = cc & 1023;
                int hh = o >> 6, d = o & 63;
                int bb = rbase >> 11, s = rbase & 2047;
                short* vt = part ? Vti : Vtr;
                ushort4 pk;
                pk.x = (unsigned short)bf16_of(acc[mi][ni][0]);
                pk.y = (unsigned short)bf16_of(acc[mi][ni][1]);
                pk.z = (unsigned short)bf16_of(acc[mi][ni][2]);
                pk.w = (unsigned short)bf16_of(acc[mi][ni][3]);
                *reinterpret_cast<ushort4*>(&vt[((size_t)(bb * 16 + hh) * 64 + d) * 2048 + s]) = pk;
            }
        }
    }
}

// ---------------------------------------------------------------------------
// Split-K flash attention (round-12 champion): K AND V staged in LDS once per
// block; raw v_sqrt/v_exp score math; swapped QK^T; flattened softmax
// (scores in [0,44.2], no max-sub); split-K x2; KVBLK=32 double-buffered.
// ---------------------------------------------------------------------------
__global__ __launch_bounds__(256) void attn_split(
    const short* __restrict__ QKhi, const short* __restrict__ QKlo,
    const short* __restrict__ Vtr, const short* __restrict__ Vti,
    float* __restrict__ Opart, float* __restrict__ Lp)
{
    __shared__ short kbuf[2][32][128];                 // 16 KB: row=key, [kr|ki], XOR slots
    __shared__ short vbuf[2][64][64];                  // 16 KB: row=d, [vr 32k|vi 32k], XOR slots
    __shared__ __align__(16) short p_lds[4][16][40];   // 5 KB per-wave P tiles
    const int tid = threadIdx.x, lane = tid & 63, wid = tid >> 6;
    const int c = lane & 15, g = lane >> 4;

    const int L = blockIdx.x;
    const int p = (L & 7) + ((L >> 9) << 3);     // (b,h) pair 0..31 (4 per XCD)
    const int j64 = (L >> 3) & 63;
    const int qt = j64 & 31;
    const int half = j64 >> 5;
    const int h = p & 15, b = p >> 4;
    const int kb0 = half * 1024;                 // first key of this block's range

    const int q0 = qt * 64 + wid * 16;
    const int mq = b * 2048 + q0 + c;

    s8v qrh[2], qrl[2], qih[2], qil[2], nqrh[2], nqrl[2];
#pragma unroll
    for (int ks = 0; ks < 2; ++ks) {
        int colr = h * 64 + ks * 32 + 8 * g;
        qrh[ks] = *reinterpret_cast<const s8v*>(&QKhi[(size_t)mq * 4096 + colr]);
        qrl[ks] = *reinterpret_cast<const s8v*>(&QKlo[(size_t)mq * 2048 + colr]);
        qih[ks] = *reinterpret_cast<const s8v*>(&QKhi[(size_t)mq * 4096 + 1024 + colr]);
        qil[ks] = *reinterpret_cast<const s8v*>(&QKlo[(size_t)mq * 2048 + 1024 + colr]);
        nqrh[ks] = qrh[ks] ^ (short)0x8000;
        nqrl[ks] = qrl[ks] ^ (short)0x8000;
    }

    const int srow = tid >> 4;                 // 0..15
    const int sslot = tid & 15;
    const int kslot_u = sslot ^ (srow & 7);
    const int gcolK = 2048 + (kslot_u >> 3) * 1024 + h * 64 + (kslot_u & 7) * 8;
    const short* gK = QKhi + (size_t)(b * 2048) * 4096 + gcolK;

    const int vlr = lane >> 3;                  // local row 0..7
    const int vs = lane & 7;                    // physical slot
    const short* gV[2];
#pragma unroll
    for (int i = 0; i < 2; ++i) {
        int d = wid * 16 + i * 8 + vlr;
        int u = vs ^ (d & 7);
        const short* base = (u < 4) ? Vtr : Vti;
        gV[i] = base + (size_t)((b * 16 + h) * 64 + d) * 2048 + (u & 3) * 8;
    }

    const f4v zero4 = {0.f, 0.f, 0.f, 0.f};
    f4v aor[4], aoi[4];
#pragma unroll
    for (int dt = 0; dt < 4; ++dt) { aor[dt] = zero4; aoi[dt] = zero4; }
    float lrun = 0.f;        // all of this lane's scores belong to q = q0 + c

    // exp(s*0.125) == exp2(s*0.125*log2e)
    const float ESC = 0.125f * 1.44269504f;

    // prologue: stage tile 0 (K + V)
#pragma unroll
    for (int i = 0; i < 2; ++i) {
        __builtin_amdgcn_global_load_lds(
            gK + (size_t)(kb0 + i * 16 + srow) * 4096,
            &kbuf[0][i * 16 + wid * 4][0], 16, 0, 0);
        __builtin_amdgcn_global_load_lds(
            gV[i] + kb0,
            &vbuf[0][wid * 16 + i * 8][0], 16, 0, 0);
    }
    __syncthreads();

    for (int kt = 0; kt < 32; ++kt) {
        const int buf = kt & 1;
        if (kt + 1 < 32) {
            const int ko = kb0 + (kt + 1) * 32;
#pragma unroll
            for (int i = 0; i < 2; ++i) {
                __builtin_amdgcn_global_load_lds(
                    gK + (size_t)(ko + i * 16 + srow) * 4096,
                    &kbuf[buf ^ 1][i * 16 + wid * 4][0], 16, 0, 0);
                __builtin_amdgcn_global_load_lds(
                    gV[i] + ko,
                    &vbuf[buf ^ 1][wid * 16 + i * 8][0], 16, 0, 0);
            }
        }

#pragma unroll
        for (int kn = 0; kn < 2; ++kn) {
            f4v sr = zero4, si = zero4;
            const int row = kn * 16 + c;
#pragma unroll
            for (int ks = 0; ks < 2; ++ks) {
                const int sl = (((ks * 4 + g) ^ (c & 7))) * 8;
                s8v krh = *reinterpret_cast<const s8v*>(&kbuf[buf][row][sl]);
                s8v kih = *reinterpret_cast<const s8v*>(&kbuf[buf][row][sl + 64]);
                // swapped operands: lane(c,g) reg j = S[q=c][k=kn*16+4g+j]
                sr = mf(krh, qrh[ks], sr); sr = mf(krh, qrl[ks], sr);
                sr = mf(kih, qih[ks], sr); sr = mf(kih, qil[ks], sr);
                si = mf(krh, qih[ks], si); si = mf(krh, qil[ks], si);
                si = mf(kih, nqrh[ks], si); si = mf(kih, nqrl[ks], si);
            }
            float pv0, pv1, pv2, pv3;
            {
                float a, e;
                a = sr[0]; e = si[0];
                pv0 = hw_exp2(hw_sqrt(__builtin_fmaf(e, e, a * a)) * ESC);
                a = sr[1]; e = si[1];
                pv1 = hw_exp2(hw_sqrt(__builtin_fmaf(e, e, a * a)) * ESC);
                a = sr[2]; e = si[2];
                pv2 = hw_exp2(hw_sqrt(__builtin_fmaf(e, e, a * a)) * ESC);
                a = sr[3]; e = si[3];
                pv3 = hw_exp2(hw_sqrt(__builtin_fmaf(e, e, a * a)) * ESC);
            }
            lrun += (pv0 + pv1) + (pv2 + pv3);
            unsigned lo32, hi32;
            asm("v_cvt_pk_bf16_f32 %0, %1, %2" : "=v"(lo32) : "v"(pv0), "v"(pv1));
            asm("v_cvt_pk_bf16_f32 %0, %1, %2" : "=v"(hi32) : "v"(pv2), "v"(pv3));
            uint2 pk2; pk2.x = lo32; pk2.y = hi32;
            *reinterpret_cast<uint2*>(&p_lds[wid][c][kn * 16 + 4 * g]) = pk2;
        }

        // PV: P is [16q x 32k] per wave; V from shared vbuf (swizzled read)
        s8v pa = *reinterpret_cast<const s8v*>(&p_lds[wid][c][8 * g]);
#pragma unroll
        for (int dt = 0; dt < 4; ++dt) {
            const int d = dt * 16 + c;
            const int sr_ = (g ^ (d & 7)) * 8;          // vr logical slot g
            const int si_ = ((4 + g) ^ (d & 7)) * 8;    // vi logical slot 4+g
            s8v vr = *reinterpret_cast<const s8v*>(&vbuf[buf][d][sr_]);
            s8v vi = *reinterpret_cast<const s8v*>(&vbuf[buf][d][si_]);
            aor[dt] = mf(pa, vr, aor[dt]);
            aoi[dt] = mf(pa, vi, aoi[dt]);
        }
        __syncthreads();   // kbuf/vbuf[buf] free; next tile staged
    }

    // row-sum: lanes c, c+16, c+32, c+48 share q = q0 + c
    {
        float r = lrun;
        r += __shfl_xor(r, 16);
        r += __shfl_xor(r, 32);
        if (g == 0)
            Lp[(size_t)half * 65536 + ((b * 16 + h) << 11) + q0 + c] = r;
    }
    // partial O (fp32) -> Opart
#pragma unroll
    for (int dt = 0; dt < 4; ++dt) {
#pragma unroll
        for (int j = 0; j < 4; ++j) {
            int row = b * 2048 + q0 + 4 * g + j;
            size_t base = ((size_t)half * 4096 + row) * 2048 + h * 64 + dt * 16 + c;
            Opart[base] = aor[dt][j];
            Opart[base + 1024] = aoi[dt][j];
        }
    }
}

// ---------------------------------------------------------------------------
// Combine split-K partials: aout = (O0 + O1) / (l0 + l1), bf16.
// ---------------------------------------------------------------------------
__global__ __launch_bounds__(256) void combine(
    const float* __restrict__ Opart, const float* __restrict__ Lp,
    short* __restrict__ aout)
{
    int idx = blockIdx.x * 256 + threadIdx.x;     // 0 .. 1048575
    int r = idx >> 8, cg = idx & 255;
    int col = cg * 8;
    int b = r >> 11, q = r & 2047;
    int h = (col & 1023) >> 6;
    int lidx = ((b * 16 + h) << 11) + q;
    float li = 1.f / (Lp[lidx] + Lp[65536 + lidx]);
    size_t o0 = (size_t)r * 2048 + col;
    float4 a0 = *reinterpret_cast<const float4*>(Opart + o0);
    float4 a1 = *reinterpret_cast<const float4*>(Opart + o0 + 4);
    float4 b0 = *reinterpret_cast<const float4*>(Opart + 8388608 + o0);
    float4 b1 = *reinterpret_cast<const float4*>(Opart + 8388608 + o0 + 4);
    s8v u;
    u[0] = bf16_of((a0.x + b0.x) * li);
    u[1] = bf16_of((a0.y + b0.y) * li);
    u[2] = bf16_of((a0.z + b0.z) * li);
    u[3] = bf16_of((a0.w + b0.w) * li);
    u[4] = bf16_of((a1.x + b1.x) * li);
    u[5] = bf16_of((a1.y + b1.y) * li);
    u[6] = bf16_of((a1.z + b1.z) * li);
    u[7] = bf16_of((a1.w + b1.w) * li);
    *reinterpret_cast<s8v*>(&aout[o0]) = u;
}

// ---------------------------------------------------------------------------
// GEMM2: attn_out [4096 x 2048] x packed o_w bf16 [2048 x 2048] -> yr|yi fp32
// ---------------------------------------------------------------------------
__global__ __launch_bounds__(256) void gemm_out(
    const short* __restrict__ A,
    const short* __restrict__ Boh,
    float* __restrict__ out)
{
    __shared__ __align__(16) short Ah[128][32], Bh[128][32];
    const int tid = threadIdx.x;
    const int lane = tid & 63, wid = tid >> 6;
    const int c = lane & 15, g = lane >> 4;
    const int wr = wid >> 1, wc = wid & 1;
    const int nt = blockIdx.x, mt = blockIdx.y;
    const int m0 = mt * 128, n0 = nt * 128;

    const f4v zero4 = {0.f, 0.f, 0.f, 0.f};
    f4v acc[4][4];
#pragma unroll
    for (int mi = 0; mi < 4; ++mi)
#pragma unroll
        for (int ni = 0; ni < 4; ++ni) acc[mi][ni] = zero4;

    const int rloc = lane >> 2;
    const int Lch = (lane & 3) ^ ((lane >> 3) & 3);
    const int arow = m0 + wid * 16 + rloc;
    const int brow = n0 + wid * 16 + rloc;
    const short* gA0 = A + (size_t)arow * 2048 + Lch * 8;
    const short* gA1 = gA0 + (size_t)64 * 2048;
    const short* gB0 = Boh + (size_t)brow * 2048 + Lch * 8;
    const short* gB1 = gB0 + (size_t)64 * 2048;

    const int cswz = (g ^ ((c >> 1) & 3)) * 8;

    for (int kt = 0; kt < 64; ++kt) {
        __syncthreads();
        __builtin_amdgcn_global_load_lds(gA0, &Ah[wid * 16][0], 16, 0, 0);
        __builtin_amdgcn_global_load_lds(gA1, &Ah[64 + wid * 16][0], 16, 0, 0);
        __builtin_amdgcn_global_load_lds(gB0, &Bh[wid * 16][0], 16, 0, 0);
        __builtin_amdgcn_global_load_lds(gB1, &Bh[64 + wid * 16][0], 16, 0, 0);
        gA0 += 32; gA1 += 32; gB0 += 32; gB1 += 32;
        __syncthreads();

        s8v af[4], bfr[4];
#pragma unroll
        for (int i = 0; i < 4; ++i) {
            af[i]  = *reinterpret_cast<const s8v*>(&Ah[wr * 64 + i * 16 + c][cswz]);
            bfr[i] = *reinterpret_cast<const s8v*>(&Bh[wc * 64 + i * 16 + c][cswz]);
        }
        __builtin_amdgcn_s_setprio(1);
#pragma unroll
        for (int mi = 0; mi < 4; ++mi)
#pragma unroll
            for (int ni = 0; ni < 4; ++ni)
                acc[mi][ni] = mf(af[mi], bfr[ni], acc[mi][ni]);
        __builtin_amdgcn_s_setprio(0);
    }

#pragma unroll
    for (int mi = 0; mi < 4; ++mi)
#pragma unroll
        for (int ni = 0; ni < 4; ++ni) {
            int col = n0 + wc * 64 + ni * 16 + c;
#pragma unroll
            for (int j = 0; j < 4; ++j) {
                int row = m0 + wr * 64 + mi * 16 + 4 * g + j;
                float v = acc[mi][ni][j];
                if (col < 1024) out[(size_t)row * 1024 + col] = v;
                else out[4194304 + (size_t)row * 1024 + (col - 1024)] = v;
            }
        }
}

extern "C" void kernel_launch(void* const* d_in, const int* in_sizes, int n_in,
                              void* d_out, int out_size, void* d_ws, size_t ws_size,
                              hipStream_t stream) {
    const float* zr  = (const float*)d_in[0];
    const float* zi  = (const float*)d_in[1];
    const float* qwr = (const float*)d_in[2];
    const float* qwi = (const float*)d_in[3];
    const float* kwr = (const float*)d_in[4];
    const float* kwi = (const float*)d_in[5];
    const float* vwr = (const float*)d_in[6];
    const float* vwi = (const float*)d_in[7];
    const float* owr = (const float*)d_in[8];
    const float* owi = (const float*)d_in[9];

    char* ws = (char*)d_ws;
    short* QKhi = (short*)(ws);                      // 33554432 B
    short* QKlo = (short*)(ws + 33554432);           // 16777216 B (Q cols only)
    short* Vtr  = (short*)(ws + 50331648);           //  8388608 B
    short* Vti  = (short*)(ws + 58720256);           //  8388608 B
    short* aout = (short*)(ws + 67108864);           // 16777216 B
    short* Zhi  = (short*)(ws + 83886080);           // 16777216 B
    short* Zlo  = (short*)(ws + 100663296);          // 16777216 B
    short* Bqh  = (short*)(ws + 117440512);          // 25165824 B
    short* Bql  = (short*)(ws + 142606336);          // 25165824 B
    short* Boh  = (short*)(ws + 167772160);          //  8388608 B  (total 176160768)
    // split-K partials alias the prep buffers (dead after gemm_q/gemm_kv):
    float* Opart = (float*)(ws + 83886080);          // 67108864 B over Zhi..Bqh(+)
    float* Lp    = (float*)(ws + 150994944);         //   524288 B inside Bql

    prep_all<<<dim3(24576), 256, 0, stream>>>(zr, zi, qwr, qwi, kwr, kwi, vwr, vwi,
                                              owr, owi, Zhi, Zlo, Bqh, Bql, Boh);
    gemm_q<<<dim3(16, 32, 1), 256, 0, stream>>>(Zhi, Zlo, Bqh, Bql, QKhi, QKlo);
    gemm_kv<<<dim3(32, 32, 1), 256, 0, stream>>>(Zhi, Bqh, QKhi, Vtr, Vti);
    attn_split<<<dim3(2048), 256, 0, stream>>>(QKhi, QKlo, Vtr, Vti, Opart, Lp);
    combine<<<dim3(4096), 256, 0, stream>>>(Opart, Lp, aout);
    gemm_out<<<dim3(16, 32, 1), 256, 0, stream>>>(aout, Boh, (float*)d_out);
}

// Round 15
// 462.821 us; speedup vs baseline: 1.0641x; 1.0070x over previous
//
#include <hip/hip_runtime.h>
#include <hip/hip_bf16.h>
#include <cmath>

typedef __attribute__((ext_vector_type(8))) short s8v;   // 8 bf16 (4 VGPR) MFMA operand / 16B chunk
typedef __attribute__((ext_vector_type(4))) float f4v;   // MFMA accumulator

__device__ __forceinline__ f4v mf(s8v a, s8v b, f4v c) {
    return __builtin_amdgcn_mfma_f32_16x16x32_bf16(a, b, c, 0, 0, 0);
}

// RNE float -> bf16 bits (finite inputs only)
__device__ __forceinline__ short bf16_of(float f) {
    unsigned u = __builtin_bit_cast(unsigned, f);
    unsigned r = (u + 0x7FFFu + ((u >> 16) & 1u)) >> 16;
    return (short)r;
}
__device__ __forceinline__ float f_of_bf16(short h) {
    return __builtin_bit_cast(float, ((unsigned)(unsigned short)h) << 16);
}
__device__ __forceinline__ void split2(float v, short& h, short& l) {
    short hh = bf16_of(v);
    h = hh;
    l = bf16_of(v - f_of_bf16(hh));
}

// fast hw sqrt/exp2 (1-ulp; inputs here are normal-range, >= 0)
__device__ __forceinline__ float hw_sqrt(float x) {
    float r;
    asm("v_sqrt_f32 %0, %1" : "=v"(r) : "v"(x));
    return r;
}
__device__ __forceinline__ float hw_exp2(float x) {
    float r;
    asm("v_exp_f32 %0, %1" : "=v"(r) : "v"(x));
    return r;
}

// ---------------------------------------------------------------------------
// Merged prep: blocks [0,8192) = z -> Zhi/Zlo; [8192,20480) = qkv weights ->
// Bqh/Bql (signs baked); [20480,24576) = o weights -> Boh.
// ---------------------------------------------------------------------------
__global__ __launch_bounds__(256) void prep_all(
    const float* __restrict__ zr, const float* __restrict__ zi,
    const float* __restrict__ qwr, const float* __restrict__ qwi,
    const float* __restrict__ kwr, const float* __restrict__ kwi,
    const float* __restrict__ vwr, const float* __restrict__ vwi,
    const float* __restrict__ owr, const float* __restrict__ owi,
    short* __restrict__ Zhi, short* __restrict__ Zlo,
    short* __restrict__ Bqh, short* __restrict__ Bql,
    short* __restrict__ Boh)
{
    int blk = blockIdx.x;
    if (blk < 8192) {
        int idx = blk * 256 + threadIdx.x;
        int m = idx >> 9, kq = idx & 511;
        const float* src = (kq < 256) ? (zr + (size_t)m * 1024 + kq * 4)
                                      : (zi + (size_t)m * 1024 + (kq - 256) * 4);
        float4 v = *reinterpret_cast<const float4*>(src);
        ushort4 hi, lo;
        short h, l;
        split2(v.x, h, l); hi.x = h; lo.x = l;
        split2(v.y, h, l); hi.y = h; lo.y = l;
        split2(v.z, h, l); hi.z = h; lo.z = l;
        split2(v.w, h, l); hi.w = h; lo.w = l;
        *reinterpret_cast<ushort4*>(&Zhi[(size_t)m * 2048 + kq * 4]) = hi;
        *reinterpret_cast<ushort4*>(&Zlo[(size_t)m * 2048 + kq * 4]) = lo;
    } else if (blk < 20480) {
        int idx = (blk - 8192) * 256 + threadIdx.x;
        int n = idx >> 9, kq = idx & 511;
        int k = kq * 4;
        int t = n >> 11, cpart = (n >> 10) & 1, o = n & 1023;
        const float* Wr = (t == 0) ? qwr : (t == 1) ? kwr : vwr;
        const float* Wi = (t == 0) ? qwi : (t == 1) ? kwi : vwi;
        const float* W;
        float sgn;
        int kk;
        if (k < 1024) { W = cpart ? Wi : Wr; sgn = 1.f; kk = k; }
        else          { W = cpart ? Wr : Wi; sgn = cpart ? 1.f : -1.f; kk = k - 1024; }
        float4 v = *reinterpret_cast<const float4*>(W + (size_t)o * 1024 + kk);
        ushort4 hi, lo;
        short h, l;
        split2(sgn * v.x, h, l); hi.x = h; lo.x = l;
        split2(sgn * v.y, h, l); hi.y = h; lo.y = l;
        split2(sgn * v.z, h, l); hi.z = h; lo.z = l;
        split2(sgn * v.w, h, l); hi.w = h; lo.w = l;
        *reinterpret_cast<ushort4*>(&Bqh[(size_t)n * 2048 + k]) = hi;
        *reinterpret_cast<ushort4*>(&Bql[(size_t)n * 2048 + k]) = lo;
    } else {
        int idx = (blk - 20480) * 256 + threadIdx.x;
        int n = idx >> 9, kq = idx & 511;
        int k = kq * 4;
        int part = n >> 10, o = n & 1023;
        const float* W;
        float sgn;
        int kk;
        if (k < 1024) { W = part ? owi : owr; sgn = 1.f; kk = k; }
        else          { W = part ? owr : owi; sgn = part ? 1.f : -1.f; kk = k - 1024; }
        float4 v = *reinterpret_cast<const float4*>(W + (size_t)o * 1024 + kk);
        ushort4 hi;
        hi.x = (unsigned short)bf16_of(sgn * v.x);
        hi.y = (unsigned short)bf16_of(sgn * v.y);
        hi.z = (unsigned short)bf16_of(sgn * v.z);
        hi.w = (unsigned short)bf16_of(sgn * v.w);
        *reinterpret_cast<ushort4*>(&Boh[(size_t)n * 2048 + k]) = hi;
    }
}

// ---------------------------------------------------------------------------
// Merged QKV GEMM: blocks [0,512) = Q (3-pass hi/lo split, [4096x2048]x[2048x2048]);
// blocks [512,1536) = K,V (single bf16 pass, [4096x2048]x[2048x4096]).
// Both paths co-resident per CU -> fills wave slots that gemm_q's 2-blocks/CU
// grid left idle. glds staging, XOR-swizzled [128][32] tiles (round 14):
// physical 16B slot = logical ^ ((row>>1)&3); lane l stages row base+(l>>2),
// source chunk (l&3)^((l>>3)&3); read col swizzle (g^((c>>1)&3))*8, 2-way banks.
// ---------------------------------------------------------------------------
__global__ __launch_bounds__(256) void gemm_qkv(
    const short* __restrict__ Zhi, const short* __restrict__ Zlo,
    const short* __restrict__ Bqh, const short* __restrict__ Bql,
    short* __restrict__ QKhi, short* __restrict__ QKlo,
    short* __restrict__ Vtr, short* __restrict__ Vti)
{
    __shared__ __align__(16) short lds[4][128][32];    // 32 KB
    const int tid = threadIdx.x;
    const int lane = tid & 63, wid = tid >> 6;
    const int c = lane & 15, g = lane >> 4;
    const int wr = wid >> 1, wc = wid & 1;

    const int rloc = lane >> 2;                       // 0..15
    const int Lch = (lane & 3) ^ ((lane >> 3) & 3);   // source chunk
    const int cswz = (g ^ ((c >> 1) & 3)) * 8;        // read-side swizzled col

    const f4v zero4 = {0.f, 0.f, 0.f, 0.f};
    f4v acc[4][4];
#pragma unroll
    for (int mi = 0; mi < 4; ++mi)
#pragma unroll
        for (int ni = 0; ni < 4; ++ni) acc[mi][ni] = zero4;

    if (blockIdx.x < 512) {
        // ---------------- Q path: 3-pass hi/lo ----------------
        const int nt = blockIdx.x & 15, mt = blockIdx.x >> 4;
        const int m0 = mt * 128, n0 = nt * 128;
        const int arow = m0 + wid * 16 + rloc;
        const int brow = n0 + wid * 16 + rloc;
        const short* gAh0 = Zhi + (size_t)arow * 2048 + Lch * 8;
        const short* gAh1 = gAh0 + (size_t)64 * 2048;
        const short* gAl0 = Zlo + (size_t)arow * 2048 + Lch * 8;
        const short* gAl1 = gAl0 + (size_t)64 * 2048;
        const short* gBh0 = Bqh + (size_t)brow * 2048 + Lch * 8;
        const short* gBh1 = gBh0 + (size_t)64 * 2048;
        const short* gBl0 = Bql + (size_t)brow * 2048 + Lch * 8;
        const short* gBl1 = gBl0 + (size_t)64 * 2048;

        for (int kt = 0; kt < 64; ++kt) {
            __syncthreads();
            __builtin_amdgcn_global_load_lds(gAh0, &lds[0][wid * 16][0], 16, 0, 0);
            __builtin_amdgcn_global_load_lds(gAh1, &lds[0][64 + wid * 16][0], 16, 0, 0);
            __builtin_amdgcn_global_load_lds(gAl0, &lds[1][wid * 16][0], 16, 0, 0);
            __builtin_amdgcn_global_load_lds(gAl1, &lds[1][64 + wid * 16][0], 16, 0, 0);
            __builtin_amdgcn_global_load_lds(gBh0, &lds[2][wid * 16][0], 16, 0, 0);
            __builtin_amdgcn_global_load_lds(gBh1, &lds[2][64 + wid * 16][0], 16, 0, 0);
            __builtin_amdgcn_global_load_lds(gBl0, &lds[3][wid * 16][0], 16, 0, 0);
            __builtin_amdgcn_global_load_lds(gBl1, &lds[3][64 + wid * 16][0], 16, 0, 0);
            gAh0 += 32; gAh1 += 32; gAl0 += 32; gAl1 += 32;
            gBh0 += 32; gBh1 += 32; gBl0 += 32; gBl1 += 32;
            __syncthreads();

            s8v ah[4], alo[4], bh[4], blo[4];
#pragma unroll
            for (int i = 0; i < 4; ++i) {
                ah[i]  = *reinterpret_cast<const s8v*>(&lds[0][wr * 64 + i * 16 + c][cswz]);
                alo[i] = *reinterpret_cast<const s8v*>(&lds[1][wr * 64 + i * 16 + c][cswz]);
                bh[i]  = *reinterpret_cast<const s8v*>(&lds[2][wc * 64 + i * 16 + c][cswz]);
                blo[i] = *reinterpret_cast<const s8v*>(&lds[3][wc * 64 + i * 16 + c][cswz]);
            }
            __builtin_amdgcn_s_setprio(1);
#pragma unroll
            for (int mi = 0; mi < 4; ++mi)
#pragma unroll
                for (int ni = 0; ni < 4; ++ni) {
                    acc[mi][ni] = mf(ah[mi], bh[ni], acc[mi][ni]);
                    acc[mi][ni] = mf(ah[mi], blo[ni], acc[mi][ni]);
                    acc[mi][ni] = mf(alo[mi], bh[ni], acc[mi][ni]);
                }
            __builtin_amdgcn_s_setprio(0);
        }

        // epilogue: Q hi + lo
#pragma unroll
        for (int mi = 0; mi < 4; ++mi) {
#pragma unroll
            for (int ni = 0; ni < 4; ++ni) {
                int col = n0 + wc * 64 + ni * 16 + c;
                int rbase = m0 + wr * 64 + mi * 16 + 4 * g;
#pragma unroll
                for (int j = 0; j < 4; ++j) {
                    short h, l;
                    split2(acc[mi][ni][j], h, l);
                    QKhi[(size_t)(rbase + j) * 4096 + col] = h;
                    QKlo[(size_t)(rbase + j) * 2048 + col] = l;
                }
            }
        }
    } else {
        // ---------------- KV path: single bf16 pass ----------------
        const int idx = blockIdx.x - 512;
        const int nt = idx & 31, mt = idx >> 5;
        const int m0 = mt * 128, n0 = 2048 + nt * 128;
        const int arow = m0 + wid * 16 + rloc;
        const int brow = n0 + wid * 16 + rloc;
        const short* gA0 = Zhi + (size_t)arow * 2048 + Lch * 8;
        const short* gA1 = gA0 + (size_t)64 * 2048;
        const short* gB0 = Bqh + (size_t)brow * 2048 + Lch * 8;
        const short* gB1 = gB0 + (size_t)64 * 2048;

        for (int kt = 0; kt < 64; ++kt) {
            __syncthreads();
            __builtin_amdgcn_global_load_lds(gA0, &lds[0][wid * 16][0], 16, 0, 0);
            __builtin_amdgcn_global_load_lds(gA1, &lds[0][64 + wid * 16][0], 16, 0, 0);
            __builtin_amdgcn_global_load_lds(gB0, &lds[2][wid * 16][0], 16, 0, 0);
            __builtin_amdgcn_global_load_lds(gB1, &lds[2][64 + wid * 16][0], 16, 0, 0);
            gA0 += 32; gA1 += 32; gB0 += 32; gB1 += 32;
            __syncthreads();

            s8v ah[4], bh[4];
#pragma unroll
            for (int i = 0; i < 4; ++i) {
                ah[i] = *reinterpret_cast<const s8v*>(&lds[0][wr * 64 + i * 16 + c][cswz]);
                bh[i] = *reinterpret_cast<const s8v*>(&lds[2][wc * 64 + i * 16 + c][cswz]);
            }
            __builtin_amdgcn_s_setprio(1);
#pragma unroll
            for (int mi = 0; mi < 4; ++mi)
#pragma unroll
                for (int ni = 0; ni < 4; ++ni)
                    acc[mi][ni] = mf(ah[mi], bh[ni], acc[mi][ni]);
            __builtin_amdgcn_s_setprio(0);
        }

        // epilogue: K cols -> QKhi; V cols -> V^T
#pragma unroll
        for (int mi = 0; mi < 4; ++mi) {
#pragma unroll
            for (int ni = 0; ni < 4; ++ni) {
                int col = n0 + wc * 64 + ni * 16 + c;
                int rbase = m0 + wr * 64 + mi * 16 + 4 * g;
                if (col < 4096) {
#pragma unroll
                    for (int j = 0; j < 4; ++j)
                        QKhi[(size_t)(rbase + j) * 4096 + col] = bf16_of(acc[mi][ni][j]);
                } else {
                    int cc = col - 4096;
                    int part = cc >> 10, o = cc & 1023;
                    int hh = o >> 6, d = o & 63;
                    int bb = rbase >> 11, s = rbase & 2047;
                    short* vt = part ? Vti : Vtr;
                    ushort4 pk;
                    pk.x = (unsigned short)bf16_of(acc[mi][ni][0]);
                    pk.y = (unsigned short)bf16_of(acc[mi][ni][1]);
                    pk.z = (unsigned short)bf16_of(acc[mi][ni][2]);
                    pk.w = (unsigned short)bf16_of(acc[mi][ni][3]);
                    *reinterpret_cast<ushort4*>(&vt[((size_t)(bb * 16 + hh) * 64 + d) * 2048 + s]) = pk;
                }
            }
        }
    }
}

// ---------------------------------------------------------------------------
// Split-K flash attention (round-12 champion): K AND V staged in LDS once per
// block; raw v_sqrt/v_exp score math; swapped QK^T; flattened softmax
// (scores in [0,44.2], no max-sub); split-K x2; KVBLK=32 double-buffered.
// ---------------------------------------------------------------------------
__global__ __launch_bounds__(256) void attn_split(
    const short* __restrict__ QKhi, const short* __restrict__ QKlo,
    const short* __restrict__ Vtr, const short* __restrict__ Vti,
    float* __restrict__ Opart, float* __restrict__ Lp)
{
    __shared__ short kbuf[2][32][128];                 // 16 KB: row=key, [kr|ki], XOR slots
    __shared__ short vbuf[2][64][64];                  // 16 KB: row=d, [vr 32k|vi 32k], XOR slots
    __shared__ __align__(16) short p_lds[4][16][40];   // 5 KB per-wave P tiles
    const int tid = threadIdx.x, lane = tid & 63, wid = tid >> 6;
    const int c = lane & 15, g = lane >> 4;

    const int L = blockIdx.x;
    const int p = (L & 7) + ((L >> 9) << 3);     // (b,h) pair 0..31 (4 per XCD)
    const int j64 = (L >> 3) & 63;
    const int qt = j64 & 31;
    const int half = j64 >> 5;
    const int h = p & 15, b = p >> 4;
    const int kb0 = half * 1024;                 // first key of this block's range

    const int q0 = qt * 64 + wid * 16;
    const int mq = b * 2048 + q0 + c;

    s8v qrh[2], qrl[2], qih[2], qil[2], nqrh[2], nqrl[2];
#pragma unroll
    for (int ks = 0; ks < 2; ++ks) {
        int colr = h * 64 + ks * 32 + 8 * g;
        qrh[ks] = *reinterpret_cast<const s8v*>(&QKhi[(size_t)mq * 4096 + colr]);
        qrl[ks] = *reinterpret_cast<const s8v*>(&QKlo[(size_t)mq * 2048 + colr]);
        qih[ks] = *reinterpret_cast<const s8v*>(&QKhi[(size_t)mq * 4096 + 1024 + colr]);
        qil[ks] = *reinterpret_cast<const s8v*>(&QKlo[(size_t)mq * 2048 + 1024 + colr]);
        nqrh[ks] = qrh[ks] ^ (short)0x8000;
        nqrl[ks] = qrl[ks] ^ (short)0x8000;
    }

    const int srow = tid >> 4;                 // 0..15
    const int sslot = tid & 15;
    const int kslot_u = sslot ^ (srow & 7);
    const int gcolK = 2048 + (kslot_u >> 3) * 1024 + h * 64 + (kslot_u & 7) * 8;
    const short* gK = QKhi + (size_t)(b * 2048) * 4096 + gcolK;

    const int vlr = lane >> 3;                  // local row 0..7
    const int vs = lane & 7;                    // physical slot
    const short* gV[2];
#pragma unroll
    for (int i = 0; i < 2; ++i) {
        int d = wid * 16 + i * 8 + vlr;
        int u = vs ^ (d & 7);
        const short* base = (u < 4) ? Vtr : Vti;
        gV[i] = base + (size_t)((b * 16 + h) * 64 + d) * 2048 + (u & 3) * 8;
    }

    const f4v zero4 = {0.f, 0.f, 0.f, 0.f};
    f4v aor[4], aoi[4];
#pragma unroll
    for (int dt = 0; dt < 4; ++dt) { aor[dt] = zero4; aoi[dt] = zero4; }
    float lrun = 0.f;        // all of this lane's scores belong to q = q0 + c

    // exp(s*0.125) == exp2(s*0.125*log2e)
    const float ESC = 0.125f * 1.44269504f;

    // prologue: stage tile 0 (K + V)
#pragma unroll
    for (int i = 0; i < 2; ++i) {
        __builtin_amdgcn_global_load_lds(
            gK + (size_t)(kb0 + i * 16 + srow) * 4096,
            &kbuf[0][i * 16 + wid * 4][0], 16, 0, 0);
        __builtin_amdgcn_global_load_lds(
            gV[i] + kb0,
            &vbuf[0][wid * 16 + i * 8][0], 16, 0, 0);
    }
    __syncthreads();

    for (int kt = 0; kt < 32; ++kt) {
        const int buf = kt & 1;
        if (kt + 1 < 32) {
            const int ko = kb0 + (kt + 1) * 32;
#pragma unroll
            for (int i = 0; i < 2; ++i) {
                __builtin_amdgcn_global_load_lds(
                    gK + (size_t)(ko + i * 16 + srow) * 4096,
                    &kbuf[buf ^ 1][i * 16 + wid * 4][0], 16, 0, 0);
                __builtin_amdgcn_global_load_lds(
                    gV[i] + ko,
                    &vbuf[buf ^ 1][wid * 16 + i * 8][0], 16, 0, 0);
            }
        }

#pragma unroll
        for (int kn = 0; kn < 2; ++kn) {
            f4v sr = zero4, si = zero4;
            const int row = kn * 16 + c;
#pragma unroll
            for (int ks = 0; ks < 2; ++ks) {
                const int sl = (((ks * 4 + g) ^ (c & 7))) * 8;
                s8v krh = *reinterpret_cast<const s8v*>(&kbuf[buf][row][sl]);
                s8v kih = *reinterpret_cast<const s8v*>(&kbuf[buf][row][sl + 64]);
                // swapped operands: lane(c,g) reg j = S[q=c][k=kn*16+4g+j]
                sr = mf(krh, qrh[ks], sr); sr = mf(krh, qrl[ks], sr);
                sr = mf(kih, qih[ks], sr); sr = mf(kih, qil[ks], sr);
                si = mf(krh, qih[ks], si); si = mf(krh, qil[ks], si);
                si = mf(kih, nqrh[ks], si); si = mf(kih, nqrl[ks], si);
            }
            float pv0, pv1, pv2, pv3;
            {
                float a, e;
                a = sr[0]; e = si[0];
                pv0 = hw_exp2(hw_sqrt(__builtin_fmaf(e, e, a * a)) * ESC);
                a = sr[1]; e = si[1];
                pv1 = hw_exp2(hw_sqrt(__builtin_fmaf(e, e, a * a)) * ESC);
                a = sr[2]; e = si[2];
                pv2 = hw_exp2(hw_sqrt(__builtin_fmaf(e, e, a * a)) * ESC);
                a = sr[3]; e = si[3];
                pv3 = hw_exp2(hw_sqrt(__builtin_fmaf(e, e, a * a)) * ESC);
            }
            lrun += (pv0 + pv1) + (pv2 + pv3);
            unsigned lo32, hi32;
            asm("v_cvt_pk_bf16_f32 %0, %1, %2" : "=v"(lo32) : "v"(pv0), "v"(pv1));
            asm("v_cvt_pk_bf16_f32 %0, %1, %2" : "=v"(hi32) : "v"(pv2), "v"(pv3));
            uint2 pk2; pk2.x = lo32; pk2.y = hi32;
            *reinterpret_cast<uint2*>(&p_lds[wid][c][kn * 16 + 4 * g]) = pk2;
        }

        // PV: P is [16q x 32k] per wave; V from shared vbuf (swizzled read)
        s8v pa = *reinterpret_cast<const s8v*>(&p_lds[wid][c][8 * g]);
#pragma unroll
        for (int dt = 0; dt < 4; ++dt) {
            const int d = dt * 16 + c;
            const int sr_ = (g ^ (d & 7)) * 8;          // vr logical slot g
            const int si_ = ((4 + g) ^ (d & 7)) * 8;    // vi logical slot 4+g
            s8v vr = *reinterpret_cast<const s8v*>(&vbuf[buf][d][sr_]);
            s8v vi = *reinterpret_cast<const s8v*>(&vbuf[buf][d][si_]);
            aor[dt] = mf(pa, vr, aor[dt]);
            aoi[dt] = mf(pa, vi, aoi[dt]);
        }
        __syncthreads();   // kbuf/vbuf[buf] free; next tile staged
    }

    // row-sum: lanes c, c+16, c+32, c+48 share q = q0 + c
    {
        float r = lrun;
        r += __shfl_xor(r, 16);
        r += __shfl_xor(r, 32);
        if (g == 0)
            Lp[(size_t)half * 65536 + ((b * 16 + h) << 11) + q0 + c] = r;
    }
    // partial O (fp32) -> Opart
#pragma unroll
    for (int dt = 0; dt < 4; ++dt) {
#pragma unroll
        for (int j = 0; j < 4; ++j) {
            int row = b * 2048 + q0 + 4 * g + j;
            size_t base = ((size_t)half * 4096 + row) * 2048 + h * 64 + dt * 16 + c;
            Opart[base] = aor[dt][j];
            Opart[base + 1024] = aoi[dt][j];
        }
    }
}

// ---------------------------------------------------------------------------
// Combine split-K partials: aout = (O0 + O1) / (l0 + l1), bf16.
// ---------------------------------------------------------------------------
__global__ __launch_bounds__(256) void combine(
    const float* __restrict__ Opart, const float* __restrict__ Lp,
    short* __restrict__ aout)
{
    int idx = blockIdx.x * 256 + threadIdx.x;     // 0 .. 1048575
    int r = idx >> 8, cg = idx & 255;
    int col = cg * 8;
    int b = r >> 11, q = r & 2047;
    int h = (col & 1023) >> 6;
    int lidx = ((b * 16 + h) << 11) + q;
    float li = 1.f / (Lp[lidx] + Lp[65536 + lidx]);
    size_t o0 = (size_t)r * 2048 + col;
    float4 a0 = *reinterpret_cast<const float4*>(Opart + o0);
    float4 a1 = *reinterpret_cast<const float4*>(Opart + o0 + 4);
    float4 b0 = *reinterpret_cast<const float4*>(Opart + 8388608 + o0);
    float4 b1 = *reinterpret_cast<const float4*>(Opart + 8388608 + o0 + 4);
    s8v u;
    u[0] = bf16_of((a0.x + b0.x) * li);
    u[1] = bf16_of((a0.y + b0.y) * li);
    u[2] = bf16_of((a0.z + b0.z) * li);
    u[3] = bf16_of((a0.w + b0.w) * li);
    u[4] = bf16_of((a1.x + b1.x) * li);
    u[5] = bf16_of((a1.y + b1.y) * li);
    u[6] = bf16_of((a1.z + b1.z) * li);
    u[7] = bf16_of((a1.w + b1.w) * li);
    *reinterpret_cast<s8v*>(&aout[o0]) = u;
}

// ---------------------------------------------------------------------------
// GEMM2: attn_out [4096 x 2048] x packed o_w bf16 [2048 x 2048] -> yr|yi fp32
// ---------------------------------------------------------------------------
__global__ __launch_bounds__(256) void gemm_out(
    const short* __restrict__ A,
    const short* __restrict__ Boh,
    float* __restrict__ out)
{
    __shared__ __align__(16) short Ah[128][32], Bh[128][32];
    const int tid = threadIdx.x;
    const int lane = tid & 63, wid = tid >> 6;
    const int c = lane & 15, g = lane >> 4;
    const int wr = wid >> 1, wc = wid & 1;
    const int nt = blockIdx.x, mt = blockIdx.y;
    const int m0 = mt * 128, n0 = nt * 128;

    const f4v zero4 = {0.f, 0.f, 0.f, 0.f};
    f4v acc[4][4];
#pragma unroll
    for (int mi = 0; mi < 4; ++mi)
#pragma unroll
        for (int ni = 0; ni < 4; ++ni) acc[mi][ni] = zero4;

    const int rloc = lane >> 2;
    const int Lch = (lane & 3) ^ ((lane >> 3) & 3);
    const int arow = m0 + wid * 16 + rloc;
    const int brow = n0 + wid * 16 + rloc;
    const short* gA0 = A + (size_t)arow * 2048 + Lch * 8;
    const short* gA1 = gA0 + (size_t)64 * 2048;
    const short* gB0 = Boh + (size_t)brow * 2048 + Lch * 8;
    const short* gB1 = gB0 + (size_t)64 * 2048;

    const int cswz = (g ^ ((c >> 1) & 3)) * 8;

    for (int kt = 0; kt < 64; ++kt) {
        __syncthreads();
        __builtin_amdgcn_global_load_lds(gA0, &Ah[wid * 16][0], 16, 0, 0);
        __builtin_amdgcn_global_load_lds(gA1, &Ah[64 + wid * 16][0], 16, 0, 0);
        __builtin_amdgcn_global_load_lds(gB0, &Bh[wid * 16][0], 16, 0, 0);
        __builtin_amdgcn_global_load_lds(gB1, &Bh[64 + wid * 16][0], 16, 0, 0);
        gA0 += 32; gA1 += 32; gB0 += 32; gB1 += 32;
        __syncthreads();

        s8v af[4], bfr[4];
#pragma unroll
        for (int i = 0; i < 4; ++i) {
            af[i]  = *reinterpret_cast<const s8v*>(&Ah[wr * 64 + i * 16 + c][cswz]);
            bfr[i] = *reinterpret_cast<const s8v*>(&Bh[wc * 64 + i * 16 + c][cswz]);
        }
        __builtin_amdgcn_s_setprio(1);
#pragma unroll
        for (int mi = 0; mi < 4; ++mi)
#pragma unroll
            for (int ni = 0; ni < 4; ++ni)
                acc[mi][ni] = mf(af[mi], bfr[ni], acc[mi][ni]);
        __builtin_amdgcn_s_setprio(0);
    }

#pragma unroll
    for (int mi = 0; mi < 4; ++mi)
#pragma unroll
        for (int ni = 0; ni < 4; ++ni) {
            int col = n0 + wc * 64 + ni * 16 + c;
#pragma unroll
            for (int j = 0; j < 4; ++j) {
                int row = m0 + wr * 64 + mi * 16 + 4 * g + j;
                float v = acc[mi][ni][j];
                if (col < 1024) out[(size_t)row * 1024 + col] = v;
                else out[4194304 + (size_t)row * 1024 + (col - 1024)] = v;
            }
        }
}

extern "C" void kernel_launch(void* const* d_in, const int* in_sizes, int n_in,
                              void* d_out, int out_size, void* d_ws, size_t ws_size,
                              hipStream_t stream) {
    const float* zr  = (const float*)d_in[0];
    const float* zi  = (const float*)d_in[1];
    const float* qwr = (const float*)d_in[2];
    const float* qwi = (const float*)d_in[3];
    const float* kwr = (const float*)d_in[4];
    const float* kwi = (const float*)d_in[5];
    const float* vwr = (const float*)d_in[6];
    const float* vwi = (const float*)d_in[7];
    const float* owr = (const float*)d_in[8];
    const float* owi = (const float*)d_in[9];

    char* ws = (char*)d_ws;
    short* QKhi = (short*)(ws);                      // 33554432 B
    short* QKlo = (short*)(ws + 33554432);           // 16777216 B (Q cols only)
    short* Vtr  = (short*)(ws + 50331648);           //  8388608 B
    short* Vti  = (short*)(ws + 58720256);           //  8388608 B
    short* aout = (short*)(ws + 67108864);           // 16777216 B
    short* Zhi  = (short*)(ws + 83886080);           // 16777216 B
    short* Zlo  = (short*)(ws + 100663296);          // 16777216 B
    short* Bqh  = (short*)(ws + 117440512);          // 25165824 B
    short* Bql  = (short*)(ws + 142606336);          // 25165824 B
    short* Boh  = (short*)(ws + 167772160);          //  8388608 B  (total 176160768)
    // split-K partials alias the prep buffers (dead after gemm_qkv):
    float* Opart = (float*)(ws + 83886080);          // 67108864 B over Zhi..Bqh(+)
    float* Lp    = (float*)(ws + 150994944);         //   524288 B inside Bql

    prep_all<<<dim3(24576), 256, 0, stream>>>(zr, zi, qwr, qwi, kwr, kwi, vwr, vwi,
                                              owr, owi, Zhi, Zlo, Bqh, Bql, Boh);
    gemm_qkv<<<dim3(1536), 256, 0, stream>>>(Zhi, Zlo, Bqh, Bql, QKhi, QKlo, Vtr, Vti);
    attn_split<<<dim3(2048), 256, 0, stream>>>(QKhi, QKlo, Vtr, Vti, Opart, Lp);
    combine<<<dim3(4096), 256, 0, stream>>>(Opart, Lp, aout);
    gemm_out<<<dim3(16, 32, 1), 256, 0, stream>>>(aout, Boh, (float*)d_out);
}

// Round 16
// 350.502 us; speedup vs baseline: 1.4051x; 1.3205x over previous
//
#include <hip/hip_runtime.h>
#include <hip/hip_bf16.h>
#include <cmath>

typedef __attribute__((ext_vector_type(8))) short s8v;   // 8 bf16 (4 VGPR) MFMA operand / 16B chunk
typedef __attribute__((ext_vector_type(4))) float f4v;   // MFMA accumulator

__device__ __forceinline__ f4v mf(s8v a, s8v b, f4v c) {
    return __builtin_amdgcn_mfma_f32_16x16x32_bf16(a, b, c, 0, 0, 0);
}

// RNE float -> bf16 bits (finite inputs only)
__device__ __forceinline__ short bf16_of(float f) {
    unsigned u = __builtin_bit_cast(unsigned, f);
    unsigned r = (u + 0x7FFFu + ((u >> 16) & 1u)) >> 16;
    return (short)r;
}

// fast hw sqrt/exp2 (1-ulp; inputs here are normal-range, >= 0)
__device__ __forceinline__ float hw_sqrt(float x) {
    float r;
    asm("v_sqrt_f32 %0, %1" : "=v"(r) : "v"(x));
    return r;
}
__device__ __forceinline__ float hw_exp2(float x) {
    float r;
    asm("v_exp_f32 %0, %1" : "=v"(r) : "v"(x));
    return r;
}

// ---------------------------------------------------------------------------
// Merged prep (single-bf16 everywhere): blocks [0,8192) = z -> Zhi;
// [8192,20480) = qkv weights -> Bqh (signs baked); [20480,24576) = o -> Boh.
// ---------------------------------------------------------------------------
__global__ __launch_bounds__(256) void prep_all(
    const float* __restrict__ zr, const float* __restrict__ zi,
    const float* __restrict__ qwr, const float* __restrict__ qwi,
    const float* __restrict__ kwr, const float* __restrict__ kwi,
    const float* __restrict__ vwr, const float* __restrict__ vwi,
    const float* __restrict__ owr, const float* __restrict__ owi,
    short* __restrict__ Zhi,
    short* __restrict__ Bqh,
    short* __restrict__ Boh)
{
    int blk = blockIdx.x;
    if (blk < 8192) {
        int idx = blk * 256 + threadIdx.x;
        int m = idx >> 9, kq = idx & 511;
        const float* src = (kq < 256) ? (zr + (size_t)m * 1024 + kq * 4)
                                      : (zi + (size_t)m * 1024 + (kq - 256) * 4);
        float4 v = *reinterpret_cast<const float4*>(src);
        ushort4 hi;
        hi.x = (unsigned short)bf16_of(v.x);
        hi.y = (unsigned short)bf16_of(v.y);
        hi.z = (unsigned short)bf16_of(v.z);
        hi.w = (unsigned short)bf16_of(v.w);
        *reinterpret_cast<ushort4*>(&Zhi[(size_t)m * 2048 + kq * 4]) = hi;
    } else if (blk < 20480) {
        int idx = (blk - 8192) * 256 + threadIdx.x;
        int n = idx >> 9, kq = idx & 511;
        int k = kq * 4;
        int t = n >> 11, cpart = (n >> 10) & 1, o = n & 1023;
        const float* Wr = (t == 0) ? qwr : (t == 1) ? kwr : vwr;
        const float* Wi = (t == 0) ? qwi : (t == 1) ? kwi : vwi;
        const float* W;
        float sgn;
        int kk;
        if (k < 1024) { W = cpart ? Wi : Wr; sgn = 1.f; kk = k; }
        else          { W = cpart ? Wr : Wi; sgn = cpart ? 1.f : -1.f; kk = k - 1024; }
        float4 v = *reinterpret_cast<const float4*>(W + (size_t)o * 1024 + kk);
        ushort4 hi;
        hi.x = (unsigned short)bf16_of(sgn * v.x);
        hi.y = (unsigned short)bf16_of(sgn * v.y);
        hi.z = (unsigned short)bf16_of(sgn * v.z);
        hi.w = (unsigned short)bf16_of(sgn * v.w);
        *reinterpret_cast<ushort4*>(&Bqh[(size_t)n * 2048 + k]) = hi;
    } else {
        int idx = (blk - 20480) * 256 + threadIdx.x;
        int n = idx >> 9, kq = idx & 511;
        int k = kq * 4;
        int part = n >> 10, o = n & 1023;
        const float* W;
        float sgn;
        int kk;
        if (k < 1024) { W = part ? owi : owr; sgn = 1.f; kk = k; }
        else          { W = part ? owr : owi; sgn = part ? 1.f : -1.f; kk = k - 1024; }
        float4 v = *reinterpret_cast<const float4*>(W + (size_t)o * 1024 + kk);
        ushort4 hi;
        hi.x = (unsigned short)bf16_of(sgn * v.x);
        hi.y = (unsigned short)bf16_of(sgn * v.y);
        hi.z = (unsigned short)bf16_of(sgn * v.z);
        hi.w = (unsigned short)bf16_of(sgn * v.w);
        *reinterpret_cast<ushort4*>(&Boh[(size_t)n * 2048 + k]) = hi;
    }
}

// ---------------------------------------------------------------------------
// Uniform QKV GEMM, single bf16 pass: [4096 x 2048] x [2048 x 6144].
// Grid 1536: nt = bx % 48 (col tile over Q|K|V), mt = bx / 48.
// glds staging, XOR-swizzled [128][32] tiles (round 14 layout):
// physical 16B slot = logical ^ ((row>>1)&3); lane l stages row base+(l>>2),
// source chunk (l&3)^((l>>3)&3); read col swizzle (g^((c>>1)&3))*8, 2-way banks.
// Epilogue: cols [0,4096) -> QKhi (Q|K); cols [4096,6144) -> V^T (Vtr/Vti).
// ---------------------------------------------------------------------------
__global__ __launch_bounds__(256) void gemm_qkv(
    const short* __restrict__ Zhi,
    const short* __restrict__ Bqh,
    short* __restrict__ QKhi,
    short* __restrict__ Vtr, short* __restrict__ Vti)
{
    __shared__ __align__(16) short Ah[128][32], Bh[128][32];   // 16 KB
    const int tid = threadIdx.x;
    const int lane = tid & 63, wid = tid >> 6;
    const int c = lane & 15, g = lane >> 4;
    const int wr = wid >> 1, wc = wid & 1;
    const int nt = blockIdx.x % 48, mt = blockIdx.x / 48;
    const int m0 = mt * 128, n0 = nt * 128;

    const f4v zero4 = {0.f, 0.f, 0.f, 0.f};
    f4v acc[4][4];
#pragma unroll
    for (int mi = 0; mi < 4; ++mi)
#pragma unroll
        for (int ni = 0; ni < 4; ++ni) acc[mi][ni] = zero4;

    const int rloc = lane >> 2;                       // 0..15
    const int Lch = (lane & 3) ^ ((lane >> 3) & 3);   // source chunk
    const int arow = m0 + wid * 16 + rloc;
    const int brow = n0 + wid * 16 + rloc;
    const short* gA0 = Zhi + (size_t)arow * 2048 + Lch * 8;
    const short* gA1 = gA0 + (size_t)64 * 2048;
    const short* gB0 = Bqh + (size_t)brow * 2048 + Lch * 8;
    const short* gB1 = gB0 + (size_t)64 * 2048;

    const int cswz = (g ^ ((c >> 1) & 3)) * 8;        // read-side swizzled col

    for (int kt = 0; kt < 64; ++kt) {
        __syncthreads();
        __builtin_amdgcn_global_load_lds(gA0, &Ah[wid * 16][0], 16, 0, 0);
        __builtin_amdgcn_global_load_lds(gA1, &Ah[64 + wid * 16][0], 16, 0, 0);
        __builtin_amdgcn_global_load_lds(gB0, &Bh[wid * 16][0], 16, 0, 0);
        __builtin_amdgcn_global_load_lds(gB1, &Bh[64 + wid * 16][0], 16, 0, 0);
        gA0 += 32; gA1 += 32; gB0 += 32; gB1 += 32;
        __syncthreads();

        s8v ah[4], bh[4];
#pragma unroll
        for (int i = 0; i < 4; ++i) {
            ah[i] = *reinterpret_cast<const s8v*>(&Ah[wr * 64 + i * 16 + c][cswz]);
            bh[i] = *reinterpret_cast<const s8v*>(&Bh[wc * 64 + i * 16 + c][cswz]);
        }
        __builtin_amdgcn_s_setprio(1);
#pragma unroll
        for (int mi = 0; mi < 4; ++mi)
#pragma unroll
            for (int ni = 0; ni < 4; ++ni)
                acc[mi][ni] = mf(ah[mi], bh[ni], acc[mi][ni]);
        __builtin_amdgcn_s_setprio(0);
    }

    // epilogue: Q,K cols -> QKhi; V cols -> V^T
#pragma unroll
    for (int mi = 0; mi < 4; ++mi) {
#pragma unroll
        for (int ni = 0; ni < 4; ++ni) {
            int col = n0 + wc * 64 + ni * 16 + c;
            int rbase = m0 + wr * 64 + mi * 16 + 4 * g;
            if (col < 4096) {
#pragma unroll
                for (int j = 0; j < 4; ++j)
                    QKhi[(size_t)(rbase + j) * 4096 + col] = bf16_of(acc[mi][ni][j]);
            } else {
                int cc = col - 4096;
                int part = cc >> 10, o = cc & 1023;
                int hh = o >> 6, d = o & 63;
                int bb = rbase >> 11, s = rbase & 2047;
                short* vt = part ? Vti : Vtr;
                ushort4 pk;
                pk.x = (unsigned short)bf16_of(acc[mi][ni][0]);
                pk.y = (unsigned short)bf16_of(acc[mi][ni][1]);
                pk.z = (unsigned short)bf16_of(acc[mi][ni][2]);
                pk.w = (unsigned short)bf16_of(acc[mi][ni][3]);
                *reinterpret_cast<ushort4*>(&vt[((size_t)(bb * 16 + hh) * 64 + d) * 2048 + s]) = pk;
            }
        }
    }
}

// ---------------------------------------------------------------------------
// Split-K flash attention, Q single-bf16 (round 16): 8 QK MFMA per kn (was 16).
// K AND V staged in LDS once per block; raw v_sqrt/v_exp score math; swapped
// QK^T; flattened softmax (scores in [0,44.2], no max-sub); split-K x2;
// KVBLK=32 double-buffered.
// ---------------------------------------------------------------------------
__global__ __launch_bounds__(256) void attn_split(
    const short* __restrict__ QKhi,
    const short* __restrict__ Vtr, const short* __restrict__ Vti,
    float* __restrict__ Opart, float* __restrict__ Lp)
{
    __shared__ short kbuf[2][32][128];                 // 16 KB: row=key, [kr|ki], XOR slots
    __shared__ short vbuf[2][64][64];                  // 16 KB: row=d, [vr 32k|vi 32k], XOR slots
    __shared__ __align__(16) short p_lds[4][16][40];   // 5 KB per-wave P tiles
    const int tid = threadIdx.x, lane = tid & 63, wid = tid >> 6;
    const int c = lane & 15, g = lane >> 4;

    const int L = blockIdx.x;
    const int p = (L & 7) + ((L >> 9) << 3);     // (b,h) pair 0..31 (4 per XCD)
    const int j64 = (L >> 3) & 63;
    const int qt = j64 & 31;
    const int half = j64 >> 5;
    const int h = p & 15, b = p >> 4;
    const int kb0 = half * 1024;                 // first key of this block's range

    const int q0 = qt * 64 + wid * 16;
    const int mq = b * 2048 + q0 + c;

    s8v qrh[2], qih[2], nqrh[2];
#pragma unroll
    for (int ks = 0; ks < 2; ++ks) {
        int colr = h * 64 + ks * 32 + 8 * g;
        qrh[ks] = *reinterpret_cast<const s8v*>(&QKhi[(size_t)mq * 4096 + colr]);
        qih[ks] = *reinterpret_cast<const s8v*>(&QKhi[(size_t)mq * 4096 + 1024 + colr]);
        nqrh[ks] = qrh[ks] ^ (short)0x8000;
    }

    const int srow = tid >> 4;                 // 0..15
    const int sslot = tid & 15;
    const int kslot_u = sslot ^ (srow & 7);
    const int gcolK = 2048 + (kslot_u >> 3) * 1024 + h * 64 + (kslot_u & 7) * 8;
    const short* gK = QKhi + (size_t)(b * 2048) * 4096 + gcolK;

    const int vlr = lane >> 3;                  // local row 0..7
    const int vs = lane & 7;                    // physical slot
    const short* gV[2];
#pragma unroll
    for (int i = 0; i < 2; ++i) {
        int d = wid * 16 + i * 8 + vlr;
        int u = vs ^ (d & 7);
        const short* base = (u < 4) ? Vtr : Vti;
        gV[i] = base + (size_t)((b * 16 + h) * 64 + d) * 2048 + (u & 3) * 8;
    }

    const f4v zero4 = {0.f, 0.f, 0.f, 0.f};
    f4v aor[4], aoi[4];
#pragma unroll
    for (int dt = 0; dt < 4; ++dt) { aor[dt] = zero4; aoi[dt] = zero4; }
    float lrun = 0.f;        // all of this lane's scores belong to q = q0 + c

    // exp(s*0.125) == exp2(s*0.125*log2e)
    const float ESC = 0.125f * 1.44269504f;

    // prologue: stage tile 0 (K + V)
#pragma unroll
    for (int i = 0; i < 2; ++i) {
        __builtin_amdgcn_global_load_lds(
            gK + (size_t)(kb0 + i * 16 + srow) * 4096,
            &kbuf[0][i * 16 + wid * 4][0], 16, 0, 0);
        __builtin_amdgcn_global_load_lds(
            gV[i] + kb0,
            &vbuf[0][wid * 16 + i * 8][0], 16, 0, 0);
    }
    __syncthreads();

    for (int kt = 0; kt < 32; ++kt) {
        const int buf = kt & 1;
        if (kt + 1 < 32) {
            const int ko = kb0 + (kt + 1) * 32;
#pragma unroll
            for (int i = 0; i < 2; ++i) {
                __builtin_amdgcn_global_load_lds(
                    gK + (size_t)(ko + i * 16 + srow) * 4096,
                    &kbuf[buf ^ 1][i * 16 + wid * 4][0], 16, 0, 0);
                __builtin_amdgcn_global_load_lds(
                    gV[i] + ko,
                    &vbuf[buf ^ 1][wid * 16 + i * 8][0], 16, 0, 0);
            }
        }

#pragma unroll
        for (int kn = 0; kn < 2; ++kn) {
            f4v sr = zero4, si = zero4;
            const int row = kn * 16 + c;
#pragma unroll
            for (int ks = 0; ks < 2; ++ks) {
                const int sl = (((ks * 4 + g) ^ (c & 7))) * 8;
                s8v krh = *reinterpret_cast<const s8v*>(&kbuf[buf][row][sl]);
                s8v kih = *reinterpret_cast<const s8v*>(&kbuf[buf][row][sl + 64]);
                // swapped operands: lane(c,g) reg j = S[q=c][k=kn*16+4g+j]
                sr = mf(krh, qrh[ks], sr);
                sr = mf(kih, qih[ks], sr);
                si = mf(krh, qih[ks], si);
                si = mf(kih, nqrh[ks], si);
            }
            float pv0, pv1, pv2, pv3;
            {
                float a, e;
                a = sr[0]; e = si[0];
                pv0 = hw_exp2(hw_sqrt(__builtin_fmaf(e, e, a * a)) * ESC);
                a = sr[1]; e = si[1];
                pv1 = hw_exp2(hw_sqrt(__builtin_fmaf(e, e, a * a)) * ESC);
                a = sr[2]; e = si[2];
                pv2 = hw_exp2(hw_sqrt(__builtin_fmaf(e, e, a * a)) * ESC);
                a = sr[3]; e = si[3];
                pv3 = hw_exp2(hw_sqrt(__builtin_fmaf(e, e, a * a)) * ESC);
            }
            lrun += (pv0 + pv1) + (pv2 + pv3);
            unsigned lo32, hi32;
            asm("v_cvt_pk_bf16_f32 %0, %1, %2" : "=v"(lo32) : "v"(pv0), "v"(pv1));
            asm("v_cvt_pk_bf16_f32 %0, %1, %2" : "=v"(hi32) : "v"(pv2), "v"(pv3));
            uint2 pk2; pk2.x = lo32; pk2.y = hi32;
            *reinterpret_cast<uint2*>(&p_lds[wid][c][kn * 16 + 4 * g]) = pk2;
        }

        // PV: P is [16q x 32k] per wave; V from shared vbuf (swizzled read)
        s8v pa = *reinterpret_cast<const s8v*>(&p_lds[wid][c][8 * g]);
#pragma unroll
        for (int dt = 0; dt < 4; ++dt) {
            const int d = dt * 16 + c;
            const int sr_ = (g ^ (d & 7)) * 8;          // vr logical slot g
            const int si_ = ((4 + g) ^ (d & 7)) * 8;    // vi logical slot 4+g
            s8v vr = *reinterpret_cast<const s8v*>(&vbuf[buf][d][sr_]);
            s8v vi = *reinterpret_cast<const s8v*>(&vbuf[buf][d][si_]);
            aor[dt] = mf(pa, vr, aor[dt]);
            aoi[dt] = mf(pa, vi, aoi[dt]);
        }
        __syncthreads();   // kbuf/vbuf[buf] free; next tile staged
    }

    // row-sum: lanes c, c+16, c+32, c+48 share q = q0 + c
    {
        float r = lrun;
        r += __shfl_xor(r, 16);
        r += __shfl_xor(r, 32);
        if (g == 0)
            Lp[(size_t)half * 65536 + ((b * 16 + h) << 11) + q0 + c] = r;
    }
    // partial O (fp32) -> Opart
#pragma unroll
    for (int dt = 0; dt < 4; ++dt) {
#pragma unroll
        for (int j = 0; j < 4; ++j) {
            int row = b * 2048 + q0 + 4 * g + j;
            size_t base = ((size_t)half * 4096 + row) * 2048 + h * 64 + dt * 16 + c;
            Opart[base] = aor[dt][j];
            Opart[base + 1024] = aoi[dt][j];
        }
    }
}

// ---------------------------------------------------------------------------
// Combine split-K partials: aout = (O0 + O1) / (l0 + l1), bf16.
// ---------------------------------------------------------------------------
__global__ __launch_bounds__(256) void combine(
    const float* __restrict__ Opart, const float* __restrict__ Lp,
    short* __restrict__ aout)
{
    int idx = blockIdx.x * 256 + threadIdx.x;     // 0 .. 1048575
    int r = idx >> 8, cg = idx & 255;
    int col = cg * 8;
    int b = r >> 11, q = r & 2047;
    int h = (col & 1023) >> 6;
    int lidx = ((b * 16 + h) << 11) + q;
    float li = 1.f / (Lp[lidx] + Lp[65536 + lidx]);
    size_t o0 = (size_t)r * 2048 + col;
    float4 a0 = *reinterpret_cast<const float4*>(Opart + o0);
    float4 a1 = *reinterpret_cast<const float4*>(Opart + o0 + 4);
    float4 b0 = *reinterpret_cast<const float4*>(Opart + 8388608 + o0);
    float4 b1 = *reinterpret_cast<const float4*>(Opart + 8388608 + o0 + 4);
    s8v u;
    u[0] = bf16_of((a0.x + b0.x) * li);
    u[1] = bf16_of((a0.y + b0.y) * li);
    u[2] = bf16_of((a0.z + b0.z) * li);
    u[3] = bf16_of((a0.w + b0.w) * li);
    u[4] = bf16_of((a1.x + b1.x) * li);
    u[5] = bf16_of((a1.y + b1.y) * li);
    u[6] = bf16_of((a1.z + b1.z) * li);
    u[7] = bf16_of((a1.w + b1.w) * li);
    *reinterpret_cast<s8v*>(&aout[o0]) = u;
}

// ---------------------------------------------------------------------------
// GEMM2: attn_out [4096 x 2048] x packed o_w bf16 [2048 x 2048] -> yr|yi fp32
// ---------------------------------------------------------------------------
__global__ __launch_bounds__(256) void gemm_out(
    const short* __restrict__ A,
    const short* __restrict__ Boh,
    float* __restrict__ out)
{
    __shared__ __align__(16) short Ah[128][32], Bh[128][32];
    const int tid = threadIdx.x;
    const int lane = tid & 63, wid = tid >> 6;
    const int c = lane & 15, g = lane >> 4;
    const int wr = wid >> 1, wc = wid & 1;
    const int nt = blockIdx.x, mt = blockIdx.y;
    const int m0 = mt * 128, n0 = nt * 128;

    const f4v zero4 = {0.f, 0.f, 0.f, 0.f};
    f4v acc[4][4];
#pragma unroll
    for (int mi = 0; mi < 4; ++mi)
#pragma unroll
        for (int ni = 0; ni < 4; ++ni) acc[mi][ni] = zero4;

    const int rloc = lane >> 2;
    const int Lch = (lane & 3) ^ ((lane >> 3) & 3);
    const int arow = m0 + wid * 16 + rloc;
    const int brow = n0 + wid * 16 + rloc;
    const short* gA0 = A + (size_t)arow * 2048 + Lch * 8;
    const short* gA1 = gA0 + (size_t)64 * 2048;
    const short* gB0 = Boh + (size_t)brow * 2048 + Lch * 8;
    const short* gB1 = gB0 + (size_t)64 * 2048;

    const int cswz = (g ^ ((c >> 1) & 3)) * 8;

    for (int kt = 0; kt < 64; ++kt) {
        __syncthreads();
        __builtin_amdgcn_global_load_lds(gA0, &Ah[wid * 16][0], 16, 0, 0);
        __builtin_amdgcn_global_load_lds(gA1, &Ah[64 + wid * 16][0], 16, 0, 0);
        __builtin_amdgcn_global_load_lds(gB0, &Bh[wid * 16][0], 16, 0, 0);
        __builtin_amdgcn_global_load_lds(gB1, &Bh[64 + wid * 16][0], 16, 0, 0);
        gA0 += 32; gA1 += 32; gB0 += 32; gB1 += 32;
        __syncthreads();

        s8v af[4], bfr[4];
#pragma unroll
        for (int i = 0; i < 4; ++i) {
            af[i]  = *reinterpret_cast<const s8v*>(&Ah[wr * 64 + i * 16 + c][cswz]);
            bfr[i] = *reinterpret_cast<const s8v*>(&Bh[wc * 64 + i * 16 + c][cswz]);
        }
        __builtin_amdgcn_s_setprio(1);
#pragma unroll
        for (int mi = 0; mi < 4; ++mi)
#pragma unroll
            for (int ni = 0; ni < 4; ++ni)
                acc[mi][ni] = mf(af[mi], bfr[ni], acc[mi][ni]);
        __builtin_amdgcn_s_setprio(0);
    }

#pragma unroll
    for (int mi = 0; mi < 4; ++mi)
#pragma unroll
        for (int ni = 0; ni < 4; ++ni) {
            int col = n0 + wc * 64 + ni * 16 + c;
#pragma unroll
            for (int j = 0; j < 4; ++j) {
                int row = m0 + wr * 64 + mi * 16 + 4 * g + j;
                float v = acc[mi][ni][j];
                if (col < 1024) out[(size_t)row * 1024 + col] = v;
                else out[4194304 + (size_t)row * 1024 + (col - 1024)] = v;
            }
        }
}

extern "C" void kernel_launch(void* const* d_in, const int* in_sizes, int n_in,
                              void* d_out, int out_size, void* d_ws, size_t ws_size,
                              hipStream_t stream) {
    const float* zr  = (const float*)d_in[0];
    const float* zi  = (const float*)d_in[1];
    const float* qwr = (const float*)d_in[2];
    const float* qwi = (const float*)d_in[3];
    const float* kwr = (const float*)d_in[4];
    const float* kwi = (const float*)d_in[5];
    const float* vwr = (const float*)d_in[6];
    const float* vwi = (const float*)d_in[7];
    const float* owr = (const float*)d_in[8];
    const float* owi = (const float*)d_in[9];

    char* ws = (char*)d_ws;
    short* QKhi = (short*)(ws);                      // 33554432 B
    short* Vtr  = (short*)(ws + 50331648);           //  8388608 B
    short* Vti  = (short*)(ws + 58720256);           //  8388608 B
    short* aout = (short*)(ws + 67108864);           // 16777216 B
    short* Zhi  = (short*)(ws + 83886080);           // 16777216 B
    short* Bqh  = (short*)(ws + 117440512);          // 25165824 B
    short* Boh  = (short*)(ws + 167772160);          //  8388608 B  (total 176160768)
    // split-K partials alias the prep buffers (dead after gemm_qkv):
    float* Opart = (float*)(ws + 83886080);          // 67108864 B over Zhi..Bqh(+)
    float* Lp    = (float*)(ws + 150994944);         //   524288 B

    prep_all<<<dim3(24576), 256, 0, stream>>>(zr, zi, qwr, qwi, kwr, kwi, vwr, vwi,
                                              owr, owi, Zhi, Bqh, Boh);
    gemm_qkv<<<dim3(1536), 256, 0, stream>>>(Zhi, Bqh, QKhi, Vtr, Vti);
    attn_split<<<dim3(2048), 256, 0, stream>>>(QKhi, Vtr, Vti, Opart, Lp);
    combine<<<dim3(4096), 256, 0, stream>>>(Opart, Lp, aout);
    gemm_out<<<dim3(16, 32, 1), 256, 0, stream>>>(aout, Boh, (float*)d_out);
}

// Round 17
// 347.465 us; speedup vs baseline: 1.4174x; 1.0087x over previous
//
#include <hip/hip_runtime.h>
#include <hip/hip_bf16.h>
#include <cmath>

typedef __attribute__((ext_vector_type(8))) short s8v;   // 8 bf16 (4 VGPR) MFMA operand / 16B chunk
typedef __attribute__((ext_vector_type(4))) float f4v;   // MFMA accumulator

__device__ __forceinline__ f4v mf(s8v a, s8v b, f4v c) {
    return __builtin_amdgcn_mfma_f32_16x16x32_bf16(a, b, c, 0, 0, 0);
}

// RNE float -> bf16 bits (finite inputs only)
__device__ __forceinline__ short bf16_of(float f) {
    unsigned u = __builtin_bit_cast(unsigned, f);
    unsigned r = (u + 0x7FFFu + ((u >> 16) & 1u)) >> 16;
    return (short)r;
}

// fast hw sqrt/exp2 (1-ulp; inputs here are normal-range, >= 0)
__device__ __forceinline__ float hw_sqrt(float x) {
    float r;
    asm("v_sqrt_f32 %0, %1" : "=v"(r) : "v"(x));
    return r;
}
__device__ __forceinline__ float hw_exp2(float x) {
    float r;
    asm("v_exp_f32 %0, %1" : "=v"(r) : "v"(x));
    return r;
}

// ---------------------------------------------------------------------------
// Merged prep (single-bf16 everywhere): blocks [0,8192) = z -> Zhi;
// [8192,20480) = qkv weights -> Bqh (signs baked); [20480,24576) = o -> Boh.
// ---------------------------------------------------------------------------
__global__ __launch_bounds__(256) void prep_all(
    const float* __restrict__ zr, const float* __restrict__ zi,
    const float* __restrict__ qwr, const float* __restrict__ qwi,
    const float* __restrict__ kwr, const float* __restrict__ kwi,
    const float* __restrict__ vwr, const float* __restrict__ vwi,
    const float* __restrict__ owr, const float* __restrict__ owi,
    short* __restrict__ Zhi,
    short* __restrict__ Bqh,
    short* __restrict__ Boh)
{
    int blk = blockIdx.x;
    if (blk < 8192) {
        int idx = blk * 256 + threadIdx.x;
        int m = idx >> 9, kq = idx & 511;
        const float* src = (kq < 256) ? (zr + (size_t)m * 1024 + kq * 4)
                                      : (zi + (size_t)m * 1024 + (kq - 256) * 4);
        float4 v = *reinterpret_cast<const float4*>(src);
        ushort4 hi;
        hi.x = (unsigned short)bf16_of(v.x);
        hi.y = (unsigned short)bf16_of(v.y);
        hi.z = (unsigned short)bf16_of(v.z);
        hi.w = (unsigned short)bf16_of(v.w);
        *reinterpret_cast<ushort4*>(&Zhi[(size_t)m * 2048 + kq * 4]) = hi;
    } else if (blk < 20480) {
        int idx = (blk - 8192) * 256 + threadIdx.x;
        int n = idx >> 9, kq = idx & 511;
        int k = kq * 4;
        int t = n >> 11, cpart = (n >> 10) & 1, o = n & 1023;
        const float* Wr = (t == 0) ? qwr : (t == 1) ? kwr : vwr;
        const float* Wi = (t == 0) ? qwi : (t == 1) ? kwi : vwi;
        const float* W;
        float sgn;
        int kk;
        if (k < 1024) { W = cpart ? Wi : Wr; sgn = 1.f; kk = k; }
        else          { W = cpart ? Wr : Wi; sgn = cpart ? 1.f : -1.f; kk = k - 1024; }
        float4 v = *reinterpret_cast<const float4*>(W + (size_t)o * 1024 + kk);
        ushort4 hi;
        hi.x = (unsigned short)bf16_of(sgn * v.x);
        hi.y = (unsigned short)bf16_of(sgn * v.y);
        hi.z = (unsigned short)bf16_of(sgn * v.z);
        hi.w = (unsigned short)bf16_of(sgn * v.w);
        *reinterpret_cast<ushort4*>(&Bqh[(size_t)n * 2048 + k]) = hi;
    } else {
        int idx = (blk - 20480) * 256 + threadIdx.x;
        int n = idx >> 9, kq = idx & 511;
        int k = kq * 4;
        int part = n >> 10, o = n & 1023;
        const float* W;
        float sgn;
        int kk;
        if (k < 1024) { W = part ? owi : owr; sgn = 1.f; kk = k; }
        else          { W = part ? owr : owi; sgn = part ? 1.f : -1.f; kk = k - 1024; }
        float4 v = *reinterpret_cast<const float4*>(W + (size_t)o * 1024 + kk);
        ushort4 hi;
        hi.x = (unsigned short)bf16_of(sgn * v.x);
        hi.y = (unsigned short)bf16_of(sgn * v.y);
        hi.z = (unsigned short)bf16_of(sgn * v.z);
        hi.w = (unsigned short)bf16_of(sgn * v.w);
        *reinterpret_cast<ushort4*>(&Boh[(size_t)n * 2048 + k]) = hi;
    }
}

// ---------------------------------------------------------------------------
// Uniform QKV GEMM, single bf16 pass: [4096 x 2048] x [2048 x 6144].
// Round 17: double-buffered glds staging (stage kt+1 into buf^1 BEFORE
// computing buf; one barrier/kt whose vmcnt(0) drain lands the prefetch) +
// col-major XCD-chunked block mapping (each XCD owns 6 disjoint nt columns
// -> each B-panel fetched by exactly one XCD's L2).
// XOR-swizzled [128][32] tiles: phys 16B slot = logical ^ ((row>>1)&3);
// lane l stages row base+(l>>2), source chunk (l&3)^((l>>3)&3);
// read col swizzle (g^((c>>1)&3))*8, 2-way banks.
// ---------------------------------------------------------------------------
__global__ __launch_bounds__(256) void gemm_qkv(
    const short* __restrict__ Zhi,
    const short* __restrict__ Bqh,
    short* __restrict__ QKhi,
    short* __restrict__ Vtr, short* __restrict__ Vti)
{
    __shared__ __align__(16) short Ah[2][128][32], Bh[2][128][32];   // 32 KB
    const int tid = threadIdx.x;
    const int lane = tid & 63, wid = tid >> 6;
    const int c = lane & 15, g = lane >> 4;
    const int wr = wid >> 1, wc = wid & 1;
    // XCD-chunked, col-major: XCD x owns L in [x*192,(x+1)*192) = nt in [x*6,x*6+6)
    const int bid = blockIdx.x;
    const int L = (bid & 7) * 192 + (bid >> 3);
    const int nt = L / 32, mt = L % 32;
    const int m0 = mt * 128, n0 = nt * 128;

    const f4v zero4 = {0.f, 0.f, 0.f, 0.f};
    f4v acc[4][4];
#pragma unroll
    for (int mi = 0; mi < 4; ++mi)
#pragma unroll
        for (int ni = 0; ni < 4; ++ni) acc[mi][ni] = zero4;

    const int rloc = lane >> 2;                       // 0..15
    const int Lch = (lane & 3) ^ ((lane >> 3) & 3);   // source chunk
    const int arow = m0 + wid * 16 + rloc;
    const int brow = n0 + wid * 16 + rloc;
    const short* gA0 = Zhi + (size_t)arow * 2048 + Lch * 8;
    const short* gA1 = gA0 + (size_t)64 * 2048;
    const short* gB0 = Bqh + (size_t)brow * 2048 + Lch * 8;
    const short* gB1 = gB0 + (size_t)64 * 2048;

    const int cswz = (g ^ ((c >> 1) & 3)) * 8;        // read-side swizzled col

    // prologue: stage kt=0 into buf 0
    __builtin_amdgcn_global_load_lds(gA0, &Ah[0][wid * 16][0], 16, 0, 0);
    __builtin_amdgcn_global_load_lds(gA1, &Ah[0][64 + wid * 16][0], 16, 0, 0);
    __builtin_amdgcn_global_load_lds(gB0, &Bh[0][wid * 16][0], 16, 0, 0);
    __builtin_amdgcn_global_load_lds(gB1, &Bh[0][64 + wid * 16][0], 16, 0, 0);
    gA0 += 32; gA1 += 32; gB0 += 32; gB1 += 32;
    __syncthreads();

    for (int kt = 0; kt < 64; ++kt) {
        const int buf = kt & 1;
        if (kt + 1 < 64) {
            __builtin_amdgcn_global_load_lds(gA0, &Ah[buf ^ 1][wid * 16][0], 16, 0, 0);
            __builtin_amdgcn_global_load_lds(gA1, &Ah[buf ^ 1][64 + wid * 16][0], 16, 0, 0);
            __builtin_amdgcn_global_load_lds(gB0, &Bh[buf ^ 1][wid * 16][0], 16, 0, 0);
            __builtin_amdgcn_global_load_lds(gB1, &Bh[buf ^ 1][64 + wid * 16][0], 16, 0, 0);
            gA0 += 32; gA1 += 32; gB0 += 32; gB1 += 32;
        }

        s8v ah[4], bh[4];
#pragma unroll
        for (int i = 0; i < 4; ++i) {
            ah[i] = *reinterpret_cast<const s8v*>(&Ah[buf][wr * 64 + i * 16 + c][cswz]);
            bh[i] = *reinterpret_cast<const s8v*>(&Bh[buf][wc * 64 + i * 16 + c][cswz]);
        }
        __builtin_amdgcn_s_setprio(1);
#pragma unroll
        for (int mi = 0; mi < 4; ++mi)
#pragma unroll
            for (int ni = 0; ni < 4; ++ni)
                acc[mi][ni] = mf(ah[mi], bh[ni], acc[mi][ni]);
        __builtin_amdgcn_s_setprio(0);
        __syncthreads();   // drains vmcnt: buf^1 staged; buf free for next stage
    }

    // epilogue: Q,K cols -> QKhi; V cols -> V^T
#pragma unroll
    for (int mi = 0; mi < 4; ++mi) {
#pragma unroll
        for (int ni = 0; ni < 4; ++ni) {
            int col = n0 + wc * 64 + ni * 16 + c;
            int rbase = m0 + wr * 64 + mi * 16 + 4 * g;
            if (col < 4096) {
#pragma unroll
                for (int j = 0; j < 4; ++j)
                    QKhi[(size_t)(rbase + j) * 4096 + col] = bf16_of(acc[mi][ni][j]);
            } else {
                int cc = col - 4096;
                int part = cc >> 10, o = cc & 1023;
                int hh = o >> 6, d = o & 63;
                int bb = rbase >> 11, s = rbase & 2047;
                short* vt = part ? Vti : Vtr;
                ushort4 pk;
                pk.x = (unsigned short)bf16_of(acc[mi][ni][0]);
                pk.y = (unsigned short)bf16_of(acc[mi][ni][1]);
                pk.z = (unsigned short)bf16_of(acc[mi][ni][2]);
                pk.w = (unsigned short)bf16_of(acc[mi][ni][3]);
                *reinterpret_cast<ushort4*>(&vt[((size_t)(bb * 16 + hh) * 64 + d) * 2048 + s]) = pk;
            }
        }
    }
}

// ---------------------------------------------------------------------------
// Split-K flash attention, Q single-bf16: 8 QK MFMA per kt-half.
// K AND V staged in LDS once per block; raw v_sqrt/v_exp score math; swapped
// QK^T; flattened softmax (scores in [0,44.2], no max-sub); split-K x2;
// KVBLK=32 double-buffered.
// ---------------------------------------------------------------------------
__global__ __launch_bounds__(256) void attn_split(
    const short* __restrict__ QKhi,
    const short* __restrict__ Vtr, const short* __restrict__ Vti,
    float* __restrict__ Opart, float* __restrict__ Lp)
{
    __shared__ short kbuf[2][32][128];                 // 16 KB: row=key, [kr|ki], XOR slots
    __shared__ short vbuf[2][64][64];                  // 16 KB: row=d, [vr 32k|vi 32k], XOR slots
    __shared__ __align__(16) short p_lds[4][16][40];   // 5 KB per-wave P tiles
    const int tid = threadIdx.x, lane = tid & 63, wid = tid >> 6;
    const int c = lane & 15, g = lane >> 4;

    const int L = blockIdx.x;
    const int p = (L & 7) + ((L >> 9) << 3);     // (b,h) pair 0..31 (4 per XCD)
    const int j64 = (L >> 3) & 63;
    const int qt = j64 & 31;
    const int half = j64 >> 5;
    const int h = p & 15, b = p >> 4;
    const int kb0 = half * 1024;                 // first key of this block's range

    const int q0 = qt * 64 + wid * 16;
    const int mq = b * 2048 + q0 + c;

    s8v qrh[2], qih[2], nqrh[2];
#pragma unroll
    for (int ks = 0; ks < 2; ++ks) {
        int colr = h * 64 + ks * 32 + 8 * g;
        qrh[ks] = *reinterpret_cast<const s8v*>(&QKhi[(size_t)mq * 4096 + colr]);
        qih[ks] = *reinterpret_cast<const s8v*>(&QKhi[(size_t)mq * 4096 + 1024 + colr]);
        nqrh[ks] = qrh[ks] ^ (short)0x8000;
    }

    const int srow = tid >> 4;                 // 0..15
    const int sslot = tid & 15;
    const int kslot_u = sslot ^ (srow & 7);
    const int gcolK = 2048 + (kslot_u >> 3) * 1024 + h * 64 + (kslot_u & 7) * 8;
    const short* gK = QKhi + (size_t)(b * 2048) * 4096 + gcolK;

    const int vlr = lane >> 3;                  // local row 0..7
    const int vs = lane & 7;                    // physical slot
    const short* gV[2];
#pragma unroll
    for (int i = 0; i < 2; ++i) {
        int d = wid * 16 + i * 8 + vlr;
        int u = vs ^ (d & 7);
        const short* base = (u < 4) ? Vtr : Vti;
        gV[i] = base + (size_t)((b * 16 + h) * 64 + d) * 2048 + (u & 3) * 8;
    }

    const f4v zero4 = {0.f, 0.f, 0.f, 0.f};
    f4v aor[4], aoi[4];
#pragma unroll
    for (int dt = 0; dt < 4; ++dt) { aor[dt] = zero4; aoi[dt] = zero4; }
    float lrun = 0.f;        // all of this lane's scores belong to q = q0 + c

    // exp(s*0.125) == exp2(s*0.125*log2e)
    const float ESC = 0.125f * 1.44269504f;

    // prologue: stage tile 0 (K + V)
#pragma unroll
    for (int i = 0; i < 2; ++i) {
        __builtin_amdgcn_global_load_lds(
            gK + (size_t)(kb0 + i * 16 + srow) * 4096,
            &kbuf[0][i * 16 + wid * 4][0], 16, 0, 0);
        __builtin_amdgcn_global_load_lds(
            gV[i] + kb0,
            &vbuf[0][wid * 16 + i * 8][0], 16, 0, 0);
    }
    __syncthreads();

    for (int kt = 0; kt < 32; ++kt) {
        const int buf = kt & 1;
        if (kt + 1 < 32) {
            const int ko = kb0 + (kt + 1) * 32;
#pragma unroll
            for (int i = 0; i < 2; ++i) {
                __builtin_amdgcn_global_load_lds(
                    gK + (size_t)(ko + i * 16 + srow) * 4096,
                    &kbuf[buf ^ 1][i * 16 + wid * 4][0], 16, 0, 0);
                __builtin_amdgcn_global_load_lds(
                    gV[i] + ko,
                    &vbuf[buf ^ 1][wid * 16 + i * 8][0], 16, 0, 0);
            }
        }

#pragma unroll
        for (int kn = 0; kn < 2; ++kn) {
            f4v sr = zero4, si = zero4;
            const int row = kn * 16 + c;
#pragma unroll
            for (int ks = 0; ks < 2; ++ks) {
                const int sl = (((ks * 4 + g) ^ (c & 7))) * 8;
                s8v krh = *reinterpret_cast<const s8v*>(&kbuf[buf][row][sl]);
                s8v kih = *reinterpret_cast<const s8v*>(&kbuf[buf][row][sl + 64]);
                // swapped operands: lane(c,g) reg j = S[q=c][k=kn*16+4g+j]
                sr = mf(krh, qrh[ks], sr);
                sr = mf(kih, qih[ks], sr);
                si = mf(krh, qih[ks], si);
                si = mf(kih, nqrh[ks], si);
            }
            float pv0, pv1, pv2, pv3;
            {
                float a, e;
                a = sr[0]; e = si[0];
                pv0 = hw_exp2(hw_sqrt(__builtin_fmaf(e, e, a * a)) * ESC);
                a = sr[1]; e = si[1];
                pv1 = hw_exp2(hw_sqrt(__builtin_fmaf(e, e, a * a)) * ESC);
                a = sr[2]; e = si[2];
                pv2 = hw_exp2(hw_sqrt(__builtin_fmaf(e, e, a * a)) * ESC);
                a = sr[3]; e = si[3];
                pv3 = hw_exp2(hw_sqrt(__builtin_fmaf(e, e, a * a)) * ESC);
            }
            lrun += (pv0 + pv1) + (pv2 + pv3);
            unsigned lo32, hi32;
            asm("v_cvt_pk_bf16_f32 %0, %1, %2" : "=v"(lo32) : "v"(pv0), "v"(pv1));
            asm("v_cvt_pk_bf16_f32 %0, %1, %2" : "=v"(hi32) : "v"(pv2), "v"(pv3));
            uint2 pk2; pk2.x = lo32; pk2.y = hi32;
            *reinterpret_cast<uint2*>(&p_lds[wid][c][kn * 16 + 4 * g]) = pk2;
        }

        // PV: P is [16q x 32k] per wave; V from shared vbuf (swizzled read)
        s8v pa = *reinterpret_cast<const s8v*>(&p_lds[wid][c][8 * g]);
#pragma unroll
        for (int dt = 0; dt < 4; ++dt) {
            const int d = dt * 16 + c;
            const int sr_ = (g ^ (d & 7)) * 8;          // vr logical slot g
            const int si_ = ((4 + g) ^ (d & 7)) * 8;    // vi logical slot 4+g
            s8v vr = *reinterpret_cast<const s8v*>(&vbuf[buf][d][sr_]);
            s8v vi = *reinterpret_cast<const s8v*>(&vbuf[buf][d][si_]);
            aor[dt] = mf(pa, vr, aor[dt]);
            aoi[dt] = mf(pa, vi, aoi[dt]);
        }
        __syncthreads();   // kbuf/vbuf[buf] free; next tile staged
    }

    // row-sum: lanes c, c+16, c+32, c+48 share q = q0 + c
    {
        float r = lrun;
        r += __shfl_xor(r, 16);
        r += __shfl_xor(r, 32);
        if (g == 0)
            Lp[(size_t)half * 65536 + ((b * 16 + h) << 11) + q0 + c] = r;
    }
    // partial O (fp32) -> Opart
#pragma unroll
    for (int dt = 0; dt < 4; ++dt) {
#pragma unroll
        for (int j = 0; j < 4; ++j) {
            int row = b * 2048 + q0 + 4 * g + j;
            size_t base = ((size_t)half * 4096 + row) * 2048 + h * 64 + dt * 16 + c;
            Opart[base] = aor[dt][j];
            Opart[base + 1024] = aoi[dt][j];
        }
    }
}

// ---------------------------------------------------------------------------
// Combine split-K partials: aout = (O0 + O1) / (l0 + l1), bf16.
// ---------------------------------------------------------------------------
__global__ __launch_bounds__(256) void combine(
    const float* __restrict__ Opart, const float* __restrict__ Lp,
    short* __restrict__ aout)
{
    int idx = blockIdx.x * 256 + threadIdx.x;     // 0 .. 1048575
    int r = idx >> 8, cg = idx & 255;
    int col = cg * 8;
    int b = r >> 11, q = r & 2047;
    int h = (col & 1023) >> 6;
    int lidx = ((b * 16 + h) << 11) + q;
    float li = 1.f / (Lp[lidx] + Lp[65536 + lidx]);
    size_t o0 = (size_t)r * 2048 + col;
    float4 a0 = *reinterpret_cast<const float4*>(Opart + o0);
    float4 a1 = *reinterpret_cast<const float4*>(Opart + o0 + 4);
    float4 b0 = *reinterpret_cast<const float4*>(Opart + 8388608 + o0);
    float4 b1 = *reinterpret_cast<const float4*>(Opart + 8388608 + o0 + 4);
    s8v u;
    u[0] = bf16_of((a0.x + b0.x) * li);
    u[1] = bf16_of((a0.y + b0.y) * li);
    u[2] = bf16_of((a0.z + b0.z) * li);
    u[3] = bf16_of((a0.w + b0.w) * li);
    u[4] = bf16_of((a1.x + b1.x) * li);
    u[5] = bf16_of((a1.y + b1.y) * li);
    u[6] = bf16_of((a1.z + b1.z) * li);
    u[7] = bf16_of((a1.w + b1.w) * li);
    *reinterpret_cast<s8v*>(&aout[o0]) = u;
}

// ---------------------------------------------------------------------------
// GEMM2: attn_out [4096 x 2048] x packed o_w bf16 [2048 x 2048] -> yr|yi fp32
// Double-buffered glds staging (round 17).
// ---------------------------------------------------------------------------
__global__ __launch_bounds__(256) void gemm_out(
    const short* __restrict__ A,
    const short* __restrict__ Boh,
    float* __restrict__ out)
{
    __shared__ __align__(16) short Ah[2][128][32], Bh[2][128][32];
    const int tid = threadIdx.x;
    const int lane = tid & 63, wid = tid >> 6;
    const int c = lane & 15, g = lane >> 4;
    const int wr = wid >> 1, wc = wid & 1;
    const int nt = blockIdx.x, mt = blockIdx.y;
    const int m0 = mt * 128, n0 = nt * 128;

    const f4v zero4 = {0.f, 0.f, 0.f, 0.f};
    f4v acc[4][4];
#pragma unroll
    for (int mi = 0; mi < 4; ++mi)
#pragma unroll
        for (int ni = 0; ni < 4; ++ni) acc[mi][ni] = zero4;

    const int rloc = lane >> 2;
    const int Lch = (lane & 3) ^ ((lane >> 3) & 3);
    const int arow = m0 + wid * 16 + rloc;
    const int brow = n0 + wid * 16 + rloc;
    const short* gA0 = A + (size_t)arow * 2048 + Lch * 8;
    const short* gA1 = gA0 + (size_t)64 * 2048;
    const short* gB0 = Boh + (size_t)brow * 2048 + Lch * 8;
    const short* gB1 = gB0 + (size_t)64 * 2048;

    const int cswz = (g ^ ((c >> 1) & 3)) * 8;

    // prologue: stage kt=0 into buf 0
    __builtin_amdgcn_global_load_lds(gA0, &Ah[0][wid * 16][0], 16, 0, 0);
    __builtin_amdgcn_global_load_lds(gA1, &Ah[0][64 + wid * 16][0], 16, 0, 0);
    __builtin_amdgcn_global_load_lds(gB0, &Bh[0][wid * 16][0], 16, 0, 0);
    __builtin_amdgcn_global_load_lds(gB1, &Bh[0][64 + wid * 16][0], 16, 0, 0);
    gA0 += 32; gA1 += 32; gB0 += 32; gB1 += 32;
    __syncthreads();

    for (int kt = 0; kt < 64; ++kt) {
        const int buf = kt & 1;
        if (kt + 1 < 64) {
            __builtin_amdgcn_global_load_lds(gA0, &Ah[buf ^ 1][wid * 16][0], 16, 0, 0);
            __builtin_amdgcn_global_load_lds(gA1, &Ah[buf ^ 1][64 + wid * 16][0], 16, 0, 0);
            __builtin_amdgcn_global_load_lds(gB0, &Bh[buf ^ 1][wid * 16][0], 16, 0, 0);
            __builtin_amdgcn_global_load_lds(gB1, &Bh[buf ^ 1][64 + wid * 16][0], 16, 0, 0);
            gA0 += 32; gA1 += 32; gB0 += 32; gB1 += 32;
        }

        s8v af[4], bfr[4];
#pragma unroll
        for (int i = 0; i < 4; ++i) {
            af[i]  = *reinterpret_cast<const s8v*>(&Ah[buf][wr * 64 + i * 16 + c][cswz]);
            bfr[i] = *reinterpret_cast<const s8v*>(&Bh[buf][wc * 64 + i * 16 + c][cswz]);
        }
        __builtin_amdgcn_s_setprio(1);
#pragma unroll
        for (int mi = 0; mi < 4; ++mi)
#pragma unroll
            for (int ni = 0; ni < 4; ++ni)
                acc[mi][ni] = mf(af[mi], bfr[ni], acc[mi][ni]);
        __builtin_amdgcn_s_setprio(0);
        __syncthreads();
    }

#pragma unroll
    for (int mi = 0; mi < 4; ++mi)
#pragma unroll
        for (int ni = 0; ni < 4; ++ni) {
            int col = n0 + wc * 64 + ni * 16 + c;
#pragma unroll
            for (int j = 0; j < 4; ++j) {
                int row = m0 + wr * 64 + mi * 16 + 4 * g + j;
                float v = acc[mi][ni][j];
                if (col < 1024) out[(size_t)row * 1024 + col] = v;
                else out[4194304 + (size_t)row * 1024 + (col - 1024)] = v;
            }
        }
}

extern "C" void kernel_launch(void* const* d_in, const int* in_sizes, int n_in,
                              void* d_out, int out_size, void* d_ws, size_t ws_size,
                              hipStream_t stream) {
    const float* zr  = (const float*)d_in[0];
    const float* zi  = (const float*)d_in[1];
    const float* qwr = (const float*)d_in[2];
    const float* qwi = (const float*)d_in[3];
    const float* kwr = (const float*)d_in[4];
    const float* kwi = (const float*)d_in[5];
    const float* vwr = (const float*)d_in[6];
    const float* vwi = (const float*)d_in[7];
    const float* owr = (const float*)d_in[8];
    const float* owi = (const float*)d_in[9];

    char* ws = (char*)d_ws;
    short* QKhi = (short*)(ws);                      // 33554432 B
    short* Vtr  = (short*)(ws + 50331648);           //  8388608 B
    short* Vti  = (short*)(ws + 58720256);           //  8388608 B
    short* aout = (short*)(ws + 67108864);           // 16777216 B
    short* Zhi  = (short*)(ws + 83886080);           // 16777216 B
    short* Bqh  = (short*)(ws + 117440512);          // 25165824 B
    short* Boh  = (short*)(ws + 167772160);          //  8388608 B  (total 176160768)
    // split-K partials alias the prep buffers (dead after gemm_qkv):
    float* Opart = (float*)(ws + 83886080);          // 67108864 B over Zhi..Bqh(+)
    float* Lp    = (float*)(ws + 150994944);         //   524288 B

    prep_all<<<dim3(24576), 256, 0, stream>>>(zr, zi, qwr, qwi, kwr, kwi, vwr, vwi,
                                              owr, owi, Zhi, Bqh, Boh);
    gemm_qkv<<<dim3(1536), 256, 0, stream>>>(Zhi, Bqh, QKhi, Vtr, Vti);
    attn_split<<<dim3(2048), 256, 0, stream>>>(QKhi, Vtr, Vti, Opart, Lp);
    combine<<<dim3(4096), 256, 0, stream>>>(Opart, Lp, aout);
    gemm_out<<<dim3(16, 32, 1), 256, 0, stream>>>(aout, Boh, (float*)d_out);
}

// Round 18
// 345.343 us; speedup vs baseline: 1.4261x; 1.0061x over previous
//
#include <hip/hip_runtime.h>
#include <hip/hip_bf16.h>
#include <cmath>

typedef __attribute__((ext_vector_type(8))) short s8v;   // 8 bf16 (4 VGPR) MFMA operand / 16B chunk
typedef __attribute__((ext_vector_type(4))) float f4v;   // MFMA accumulator

__device__ __forceinline__ f4v mf(s8v a, s8v b, f4v c) {
    return __builtin_amdgcn_mfma_f32_16x16x32_bf16(a, b, c, 0, 0, 0);
}

// RNE float -> bf16 bits (finite inputs only)
__device__ __forceinline__ short bf16_of(float f) {
    unsigned u = __builtin_bit_cast(unsigned, f);
    unsigned r = (u + 0x7FFFu + ((u >> 16) & 1u)) >> 16;
    return (short)r;
}
__device__ __forceinline__ float f_of_bf16(unsigned short h) {
    return __builtin_bit_cast(float, ((unsigned)h) << 16);
}

// fast hw sqrt/exp2 (1-ulp; inputs here are normal-range, >= 0)
__device__ __forceinline__ float hw_sqrt(float x) {
    float r;
    asm("v_sqrt_f32 %0, %1" : "=v"(r) : "v"(x));
    return r;
}
__device__ __forceinline__ float hw_exp2(float x) {
    float r;
    asm("v_exp_f32 %0, %1" : "=v"(r) : "v"(x));
    return r;
}

// exp(s*0.125) == exp2(s*0.125*log2e); folded into Q at gemm_qkv epilogue
#define ESC_F 0.18033688f

// ---------------------------------------------------------------------------
// Merged prep (single-bf16 everywhere): blocks [0,8192) = z -> Zhi;
// [8192,20480) = qkv weights -> Bqh (signs baked); [20480,24576) = o -> Boh.
// ---------------------------------------------------------------------------
__global__ __launch_bounds__(256) void prep_all(
    const float* __restrict__ zr, const float* __restrict__ zi,
    const float* __restrict__ qwr, const float* __restrict__ qwi,
    const float* __restrict__ kwr, const float* __restrict__ kwi,
    const float* __restrict__ vwr, const float* __restrict__ vwi,
    const float* __restrict__ owr, const float* __restrict__ owi,
    short* __restrict__ Zhi,
    short* __restrict__ Bqh,
    short* __restrict__ Boh)
{
    int blk = blockIdx.x;
    if (blk < 8192) {
        int idx = blk * 256 + threadIdx.x;
        int m = idx >> 9, kq = idx & 511;
        const float* src = (kq < 256) ? (zr + (size_t)m * 1024 + kq * 4)
                                      : (zi + (size_t)m * 1024 + (kq - 256) * 4);
        float4 v = *reinterpret_cast<const float4*>(src);
        ushort4 hi;
        hi.x = (unsigned short)bf16_of(v.x);
        hi.y = (unsigned short)bf16_of(v.y);
        hi.z = (unsigned short)bf16_of(v.z);
        hi.w = (unsigned short)bf16_of(v.w);
        *reinterpret_cast<ushort4*>(&Zhi[(size_t)m * 2048 + kq * 4]) = hi;
    } else if (blk < 20480) {
        int idx = (blk - 8192) * 256 + threadIdx.x;
        int n = idx >> 9, kq = idx & 511;
        int k = kq * 4;
        int t = n >> 11, cpart = (n >> 10) & 1, o = n & 1023;
        const float* Wr = (t == 0) ? qwr : (t == 1) ? kwr : vwr;
        const float* Wi = (t == 0) ? qwi : (t == 1) ? kwi : vwi;
        const float* W;
        float sgn;
        int kk;
        if (k < 1024) { W = cpart ? Wi : Wr; sgn = 1.f; kk = k; }
        else          { W = cpart ? Wr : Wi; sgn = cpart ? 1.f : -1.f; kk = k - 1024; }
        float4 v = *reinterpret_cast<const float4*>(W + (size_t)o * 1024 + kk);
        ushort4 hi;
        hi.x = (unsigned short)bf16_of(sgn * v.x);
        hi.y = (unsigned short)bf16_of(sgn * v.y);
        hi.z = (unsigned short)bf16_of(sgn * v.z);
        hi.w = (unsigned short)bf16_of(sgn * v.w);
        *reinterpret_cast<ushort4*>(&Bqh[(size_t)n * 2048 + k]) = hi;
    } else {
        int idx = (blk - 20480) * 256 + threadIdx.x;
        int n = idx >> 9, kq = idx & 511;
        int k = kq * 4;
        int part = n >> 10, o = n & 1023;
        const float* W;
        float sgn;
        int kk;
        if (k < 1024) { W = part ? owi : owr; sgn = 1.f; kk = k; }
        else          { W = part ? owr : owi; sgn = part ? 1.f : -1.f; kk = k - 1024; }
        float4 v = *reinterpret_cast<const float4*>(W + (size_t)o * 1024 + kk);
        ushort4 hi;
        hi.x = (unsigned short)bf16_of(sgn * v.x);
        hi.y = (unsigned short)bf16_of(sgn * v.y);
        hi.z = (unsigned short)bf16_of(sgn * v.z);
        hi.w = (unsigned short)bf16_of(sgn * v.w);
        *reinterpret_cast<ushort4*>(&Boh[(size_t)n * 2048 + k]) = hi;
    }
}

// ---------------------------------------------------------------------------
// Uniform QKV GEMM, single bf16 pass: [4096 x 2048] x [2048 x 6144].
// Double-buffered glds staging; XCD-chunked col-major block mapping.
// Q columns (<2048) are prescaled by ESC in the epilogue so attention's
// score math skips the per-score scale multiply.
// XOR-swizzled [128][32] tiles: phys 16B slot = logical ^ ((row>>1)&3);
// lane l stages row base+(l>>2), source chunk (l&3)^((l>>3)&3);
// read col swizzle (g^((c>>1)&3))*8, 2-way banks.
// ---------------------------------------------------------------------------
__global__ __launch_bounds__(256) void gemm_qkv(
    const short* __restrict__ Zhi,
    const short* __restrict__ Bqh,
    short* __restrict__ QKhi,
    short* __restrict__ Vtr, short* __restrict__ Vti)
{
    __shared__ __align__(16) short Ah[2][128][32], Bh[2][128][32];   // 32 KB
    const int tid = threadIdx.x;
    const int lane = tid & 63, wid = tid >> 6;
    const int c = lane & 15, g = lane >> 4;
    const int wr = wid >> 1, wc = wid & 1;
    const int bid = blockIdx.x;
    const int L = (bid & 7) * 192 + (bid >> 3);
    const int nt = L / 32, mt = L % 32;
    const int m0 = mt * 128, n0 = nt * 128;

    const f4v zero4 = {0.f, 0.f, 0.f, 0.f};
    f4v acc[4][4];
#pragma unroll
    for (int mi = 0; mi < 4; ++mi)
#pragma unroll
        for (int ni = 0; ni < 4; ++ni) acc[mi][ni] = zero4;

    const int rloc = lane >> 2;                       // 0..15
    const int Lch = (lane & 3) ^ ((lane >> 3) & 3);   // source chunk
    const int arow = m0 + wid * 16 + rloc;
    const int brow = n0 + wid * 16 + rloc;
    const short* gA0 = Zhi + (size_t)arow * 2048 + Lch * 8;
    const short* gA1 = gA0 + (size_t)64 * 2048;
    const short* gB0 = Bqh + (size_t)brow * 2048 + Lch * 8;
    const short* gB1 = gB0 + (size_t)64 * 2048;

    const int cswz = (g ^ ((c >> 1) & 3)) * 8;        // read-side swizzled col

    // prologue: stage kt=0 into buf 0
    __builtin_amdgcn_global_load_lds(gA0, &Ah[0][wid * 16][0], 16, 0, 0);
    __builtin_amdgcn_global_load_lds(gA1, &Ah[0][64 + wid * 16][0], 16, 0, 0);
    __builtin_amdgcn_global_load_lds(gB0, &Bh[0][wid * 16][0], 16, 0, 0);
    __builtin_amdgcn_global_load_lds(gB1, &Bh[0][64 + wid * 16][0], 16, 0, 0);
    gA0 += 32; gA1 += 32; gB0 += 32; gB1 += 32;
    __syncthreads();

    for (int kt = 0; kt < 64; ++kt) {
        const int buf = kt & 1;
        if (kt + 1 < 64) {
            __builtin_amdgcn_global_load_lds(gA0, &Ah[buf ^ 1][wid * 16][0], 16, 0, 0);
            __builtin_amdgcn_global_load_lds(gA1, &Ah[buf ^ 1][64 + wid * 16][0], 16, 0, 0);
            __builtin_amdgcn_global_load_lds(gB0, &Bh[buf ^ 1][wid * 16][0], 16, 0, 0);
            __builtin_amdgcn_global_load_lds(gB1, &Bh[buf ^ 1][64 + wid * 16][0], 16, 0, 0);
            gA0 += 32; gA1 += 32; gB0 += 32; gB1 += 32;
        }

        s8v ah[4], bh[4];
#pragma unroll
        for (int i = 0; i < 4; ++i) {
            ah[i] = *reinterpret_cast<const s8v*>(&Ah[buf][wr * 64 + i * 16 + c][cswz]);
            bh[i] = *reinterpret_cast<const s8v*>(&Bh[buf][wc * 64 + i * 16 + c][cswz]);
        }
        __builtin_amdgcn_s_setprio(1);
#pragma unroll
        for (int mi = 0; mi < 4; ++mi)
#pragma unroll
            for (int ni = 0; ni < 4; ++ni)
                acc[mi][ni] = mf(ah[mi], bh[ni], acc[mi][ni]);
        __builtin_amdgcn_s_setprio(0);
        __syncthreads();   // drains vmcnt: buf^1 staged; buf free for next stage
    }

    // epilogue: Q cols (prescaled by ESC), K cols -> QKhi; V cols -> V^T
#pragma unroll
    for (int mi = 0; mi < 4; ++mi) {
#pragma unroll
        for (int ni = 0; ni < 4; ++ni) {
            int col = n0 + wc * 64 + ni * 16 + c;
            int rbase = m0 + wr * 64 + mi * 16 + 4 * g;
            if (col < 2048) {
#pragma unroll
                for (int j = 0; j < 4; ++j)
                    QKhi[(size_t)(rbase + j) * 4096 + col] = bf16_of(ESC_F * acc[mi][ni][j]);
            } else if (col < 4096) {
#pragma unroll
                for (int j = 0; j < 4; ++j)
                    QKhi[(size_t)(rbase + j) * 4096 + col] = bf16_of(acc[mi][ni][j]);
            } else {
                int cc = col - 4096;
                int part = cc >> 10, o = cc & 1023;
                int hh = o >> 6, d = o & 63;
                int bb = rbase >> 11, s = rbase & 2047;
                short* vt = part ? Vti : Vtr;
                ushort4 pk;
                pk.x = (unsigned short)bf16_of(acc[mi][ni][0]);
                pk.y = (unsigned short)bf16_of(acc[mi][ni][1]);
                pk.z = (unsigned short)bf16_of(acc[mi][ni][2]);
                pk.w = (unsigned short)bf16_of(acc[mi][ni][3]);
                *reinterpret_cast<ushort4*>(&vt[((size_t)(bb * 16 + hh) * 64 + d) * 2048 + s]) = pk;
            }
        }
    }
}

// ---------------------------------------------------------------------------
// Split-K flash attention, Q single-bf16 and ESC-prescaled: score math is
// {mul, fma, sqrt, exp2} per score. K AND V staged in LDS once per block;
// raw v_sqrt/v_exp; swapped QK^T; flattened softmax (scores in [0,44.2],
// no max-sub); split-K x2; KVBLK=32 double-buffered. Partials in bf16.
// ---------------------------------------------------------------------------
__global__ __launch_bounds__(256) void attn_split(
    const short* __restrict__ QKhi,
    const short* __restrict__ Vtr, const short* __restrict__ Vti,
    short* __restrict__ Opart, float* __restrict__ Lp)
{
    __shared__ short kbuf[2][32][128];                 // 16 KB: row=key, [kr|ki], XOR slots
    __shared__ short vbuf[2][64][64];                  // 16 KB: row=d, [vr 32k|vi 32k], XOR slots
    __shared__ __align__(16) short p_lds[4][16][40];   // 5 KB per-wave P tiles
    const int tid = threadIdx.x, lane = tid & 63, wid = tid >> 6;
    const int c = lane & 15, g = lane >> 4;

    const int L = blockIdx.x;
    const int p = (L & 7) + ((L >> 9) << 3);     // (b,h) pair 0..31 (4 per XCD)
    const int j64 = (L >> 3) & 63;
    const int qt = j64 & 31;
    const int half = j64 >> 5;
    const int h = p & 15, b = p >> 4;
    const int kb0 = half * 1024;                 // first key of this block's range

    const int q0 = qt * 64 + wid * 16;
    const int mq = b * 2048 + q0 + c;

    s8v qrh[2], qih[2], nqrh[2];
#pragma unroll
    for (int ks = 0; ks < 2; ++ks) {
        int colr = h * 64 + ks * 32 + 8 * g;
        qrh[ks] = *reinterpret_cast<const s8v*>(&QKhi[(size_t)mq * 4096 + colr]);
        qih[ks] = *reinterpret_cast<const s8v*>(&QKhi[(size_t)mq * 4096 + 1024 + colr]);
        nqrh[ks] = qrh[ks] ^ (short)0x8000;
    }

    const int srow = tid >> 4;                 // 0..15
    const int sslot = tid & 15;
    const int kslot_u = sslot ^ (srow & 7);
    const int gcolK = 2048 + (kslot_u >> 3) * 1024 + h * 64 + (kslot_u & 7) * 8;
    const short* gK = QKhi + (size_t)(b * 2048) * 4096 + gcolK;

    const int vlr = lane >> 3;                  // local row 0..7
    const int vs = lane & 7;                    // physical slot
    const short* gV[2];
#pragma unroll
    for (int i = 0; i < 2; ++i) {
        int d = wid * 16 + i * 8 + vlr;
        int u = vs ^ (d & 7);
        const short* base = (u < 4) ? Vtr : Vti;
        gV[i] = base + (size_t)((b * 16 + h) * 64 + d) * 2048 + (u & 3) * 8;
    }

    const f4v zero4 = {0.f, 0.f, 0.f, 0.f};
    f4v aor[4], aoi[4];
#pragma unroll
    for (int dt = 0; dt < 4; ++dt) { aor[dt] = zero4; aoi[dt] = zero4; }
    float lrun = 0.f;        // all of this lane's scores belong to q = q0 + c

    // prologue: stage tile 0 (K + V)
#pragma unroll
    for (int i = 0; i < 2; ++i) {
        __builtin_amdgcn_global_load_lds(
            gK + (size_t)(kb0 + i * 16 + srow) * 4096,
            &kbuf[0][i * 16 + wid * 4][0], 16, 0, 0);
        __builtin_amdgcn_global_load_lds(
            gV[i] + kb0,
            &vbuf[0][wid * 16 + i * 8][0], 16, 0, 0);
    }
    __syncthreads();

    for (int kt = 0; kt < 32; ++kt) {
        const int buf = kt & 1;
        if (kt + 1 < 32) {
            const int ko = kb0 + (kt + 1) * 32;
#pragma unroll
            for (int i = 0; i < 2; ++i) {
                __builtin_amdgcn_global_load_lds(
                    gK + (size_t)(ko + i * 16 + srow) * 4096,
                    &kbuf[buf ^ 1][i * 16 + wid * 4][0], 16, 0, 0);
                __builtin_amdgcn_global_load_lds(
                    gV[i] + ko,
                    &vbuf[buf ^ 1][wid * 16 + i * 8][0], 16, 0, 0);
            }
        }

#pragma unroll
        for (int kn = 0; kn < 2; ++kn) {
            f4v sr = zero4, si = zero4;
            const int row = kn * 16 + c;
#pragma unroll
            for (int ks = 0; ks < 2; ++ks) {
                const int sl = (((ks * 4 + g) ^ (c & 7))) * 8;
                s8v krh = *reinterpret_cast<const s8v*>(&kbuf[buf][row][sl]);
                s8v kih = *reinterpret_cast<const s8v*>(&kbuf[buf][row][sl + 64]);
                // swapped operands: lane(c,g) reg j = S[q=c][k=kn*16+4g+j]
                sr = mf(krh, qrh[ks], sr);
                sr = mf(kih, qih[ks], sr);
                si = mf(krh, qih[ks], si);
                si = mf(kih, nqrh[ks], si);
            }
            float pv0, pv1, pv2, pv3;
            {
                float a, e;
                a = sr[0]; e = si[0];
                pv0 = hw_exp2(hw_sqrt(__builtin_fmaf(e, e, a * a)));
                a = sr[1]; e = si[1];
                pv1 = hw_exp2(hw_sqrt(__builtin_fmaf(e, e, a * a)));
                a = sr[2]; e = si[2];
                pv2 = hw_exp2(hw_sqrt(__builtin_fmaf(e, e, a * a)));
                a = sr[3]; e = si[3];
                pv3 = hw_exp2(hw_sqrt(__builtin_fmaf(e, e, a * a)));
            }
            lrun += (pv0 + pv1) + (pv2 + pv3);
            unsigned lo32, hi32;
            asm("v_cvt_pk_bf16_f32 %0, %1, %2" : "=v"(lo32) : "v"(pv0), "v"(pv1));
            asm("v_cvt_pk_bf16_f32 %0, %1, %2" : "=v"(hi32) : "v"(pv2), "v"(pv3));
            uint2 pk2; pk2.x = lo32; pk2.y = hi32;
            *reinterpret_cast<uint2*>(&p_lds[wid][c][kn * 16 + 4 * g]) = pk2;
        }

        // PV: P is [16q x 32k] per wave; V from shared vbuf (swizzled read)
        s8v pa = *reinterpret_cast<const s8v*>(&p_lds[wid][c][8 * g]);
#pragma unroll
        for (int dt = 0; dt < 4; ++dt) {
            const int d = dt * 16 + c;
            const int sr_ = (g ^ (d & 7)) * 8;          // vr logical slot g
            const int si_ = ((4 + g) ^ (d & 7)) * 8;    // vi logical slot 4+g
            s8v vr = *reinterpret_cast<const s8v*>(&vbuf[buf][d][sr_]);
            s8v vi = *reinterpret_cast<const s8v*>(&vbuf[buf][d][si_]);
            aor[dt] = mf(pa, vr, aor[dt]);
            aoi[dt] = mf(pa, vi, aoi[dt]);
        }
        __syncthreads();   // kbuf/vbuf[buf] free; next tile staged
    }

    // row-sum: lanes c, c+16, c+32, c+48 share q = q0 + c
    {
        float r = lrun;
        r += __shfl_xor(r, 16);
        r += __shfl_xor(r, 32);
        if (g == 0)
            Lp[(size_t)half * 65536 + ((b * 16 + h) << 11) + q0 + c] = r;
    }
    // partial O (bf16) -> Opart
#pragma unroll
    for (int dt = 0; dt < 4; ++dt) {
#pragma unroll
        for (int j = 0; j < 4; ++j) {
            int row = b * 2048 + q0 + 4 * g + j;
            size_t base = ((size_t)half * 4096 + row) * 2048 + h * 64 + dt * 16 + c;
            Opart[base] = bf16_of(aor[dt][j]);
            Opart[base + 1024] = bf16_of(aoi[dt][j]);
        }
    }
}

// ---------------------------------------------------------------------------
// Combine split-K partials (bf16): aout = (O0 + O1) / (l0 + l1), bf16.
// ---------------------------------------------------------------------------
__global__ __launch_bounds__(256) void combine(
    const unsigned short* __restrict__ Opart, const float* __restrict__ Lp,
    short* __restrict__ aout)
{
    int idx = blockIdx.x * 256 + threadIdx.x;     // 0 .. 1048575
    int r = idx >> 8, cg = idx & 255;
    int col = cg * 8;
    int b = r >> 11, q = r & 2047;
    int h = (col & 1023) >> 6;
    int lidx = ((b * 16 + h) << 11) + q;
    float li = 1.f / (Lp[lidx] + Lp[65536 + lidx]);
    size_t o0 = (size_t)r * 2048 + col;
    ushort4 a0 = *reinterpret_cast<const ushort4*>(Opart + o0);
    ushort4 a1 = *reinterpret_cast<const ushort4*>(Opart + o0 + 4);
    ushort4 b0 = *reinterpret_cast<const ushort4*>(Opart + 8388608 + o0);
    ushort4 b1 = *reinterpret_cast<const ushort4*>(Opart + 8388608 + o0 + 4);
    s8v u;
    u[0] = bf16_of((f_of_bf16(a0.x) + f_of_bf16(b0.x)) * li);
    u[1] = bf16_of((f_of_bf16(a0.y) + f_of_bf16(b0.y)) * li);
    u[2] = bf16_of((f_of_bf16(a0.z) + f_of_bf16(b0.z)) * li);
    u[3] = bf16_of((f_of_bf16(a0.w) + f_of_bf16(b0.w)) * li);
    u[4] = bf16_of((f_of_bf16(a1.x) + f_of_bf16(b1.x)) * li);
    u[5] = bf16_of((f_of_bf16(a1.y) + f_of_bf16(b1.y)) * li);
    u[6] = bf16_of((f_of_bf16(a1.z) + f_of_bf16(b1.z)) * li);
    u[7] = bf16_of((f_of_bf16(a1.w) + f_of_bf16(b1.w)) * li);
    *reinterpret_cast<s8v*>(&aout[o0]) = u;
}

// ---------------------------------------------------------------------------
// GEMM2: attn_out [4096 x 2048] x packed o_w bf16 [2048 x 2048] -> yr|yi fp32
// Double-buffered glds staging.
// ---------------------------------------------------------------------------
__global__ __launch_bounds__(256) void gemm_out(
    const short* __restrict__ A,
    const short* __restrict__ Boh,
    float* __restrict__ out)
{
    __shared__ __align__(16) short Ah[2][128][32], Bh[2][128][32];
    const int tid = threadIdx.x;
    const int lane = tid & 63, wid = tid >> 6;
    const int c = lane & 15, g = lane >> 4;
    const int wr = wid >> 1, wc = wid & 1;
    const int nt = blockIdx.x, mt = blockIdx.y;
    const int m0 = mt * 128, n0 = nt * 128;

    const f4v zero4 = {0.f, 0.f, 0.f, 0.f};
    f4v acc[4][4];
#pragma unroll
    for (int mi = 0; mi < 4; ++mi)
#pragma unroll
        for (int ni = 0; ni < 4; ++ni) acc[mi][ni] = zero4;

    const int rloc = lane >> 2;
    const int Lch = (lane & 3) ^ ((lane >> 3) & 3);
    const int arow = m0 + wid * 16 + rloc;
    const int brow = n0 + wid * 16 + rloc;
    const short* gA0 = A + (size_t)arow * 2048 + Lch * 8;
    const short* gA1 = gA0 + (size_t)64 * 2048;
    const short* gB0 = Boh + (size_t)brow * 2048 + Lch * 8;
    const short* gB1 = gB0 + (size_t)64 * 2048;

    const int cswz = (g ^ ((c >> 1) & 3)) * 8;

    // prologue: stage kt=0 into buf 0
    __builtin_amdgcn_global_load_lds(gA0, &Ah[0][wid * 16][0], 16, 0, 0);
    __builtin_amdgcn_global_load_lds(gA1, &Ah[0][64 + wid * 16][0], 16, 0, 0);
    __builtin_amdgcn_global_load_lds(gB0, &Bh[0][wid * 16][0], 16, 0, 0);
    __builtin_amdgcn_global_load_lds(gB1, &Bh[0][64 + wid * 16][0], 16, 0, 0);
    gA0 += 32; gA1 += 32; gB0 += 32; gB1 += 32;
    __syncthreads();

    for (int kt = 0; kt < 64; ++kt) {
        const int buf = kt & 1;
        if (kt + 1 < 64) {
            __builtin_amdgcn_global_load_lds(gA0, &Ah[buf ^ 1][wid * 16][0], 16, 0, 0);
            __builtin_amdgcn_global_load_lds(gA1, &Ah[buf ^ 1][64 + wid * 16][0], 16, 0, 0);
            __builtin_amdgcn_global_load_lds(gB0, &Bh[buf ^ 1][wid * 16][0], 16, 0, 0);
            __builtin_amdgcn_global_load_lds(gB1, &Bh[buf ^ 1][64 + wid * 16][0], 16, 0, 0);
            gA0 += 32; gA1 += 32; gB0 += 32; gB1 += 32;
        }

        s8v af[4], bfr[4];
#pragma unroll
        for (int i = 0; i < 4; ++i) {
            af[i]  = *reinterpret_cast<const s8v*>(&Ah[buf][wr * 64 + i * 16 + c][cswz]);
            bfr[i] = *reinterpret_cast<const s8v*>(&Bh[buf][wc * 64 + i * 16 + c][cswz]);
        }
        __builtin_amdgcn_s_setprio(1);
#pragma unroll
        for (int mi = 0; mi < 4; ++mi)
#pragma unroll
            for (int ni = 0; ni < 4; ++ni)
                acc[mi][ni] = mf(af[mi], bfr[ni], acc[mi][ni]);
        __builtin_amdgcn_s_setprio(0);
        __syncthreads();
    }

#pragma unroll
    for (int mi = 0; mi < 4; ++mi)
#pragma unroll
        for (int ni = 0; ni < 4; ++ni) {
            int col = n0 + wc * 64 + ni * 16 + c;
#pragma unroll
            for (int j = 0; j < 4; ++j) {
                int row = m0 + wr * 64 + mi * 16 + 4 * g + j;
                float v = acc[mi][ni][j];
                if (col < 1024) out[(size_t)row * 1024 + col] = v;
                else out[4194304 + (size_t)row * 1024 + (col - 1024)] = v;
            }
        }
}

extern "C" void kernel_launch(void* const* d_in, const int* in_sizes, int n_in,
                              void* d_out, int out_size, void* d_ws, size_t ws_size,
                              hipStream_t stream) {
    const float* zr  = (const float*)d_in[0];
    const float* zi  = (const float*)d_in[1];
    const float* qwr = (const float*)d_in[2];
    const float* qwi = (const float*)d_in[3];
    const float* kwr = (const float*)d_in[4];
    const float* kwi = (const float*)d_in[5];
    const float* vwr = (const float*)d_in[6];
    const float* vwi = (const float*)d_in[7];
    const float* owr = (const float*)d_in[8];
    const float* owi = (const float*)d_in[9];

    char* ws = (char*)d_ws;
    short* QKhi = (short*)(ws);                      // 33554432 B
    short* Vtr  = (short*)(ws + 50331648);           //  8388608 B
    short* Vti  = (short*)(ws + 58720256);           //  8388608 B
    short* aout = (short*)(ws + 67108864);           // 16777216 B
    short* Zhi  = (short*)(ws + 83886080);           // 16777216 B
    short* Bqh  = (short*)(ws + 117440512);          // 25165824 B
    short* Boh  = (short*)(ws + 167772160);          //  8388608 B  (total 176160768)
    // split-K partials alias the prep buffers (dead after gemm_qkv):
    short* Opart = (short*)(ws + 83886080);          // 33554432 B (bf16) over Zhi..Bqh
    float* Lp    = (float*)(ws + 150994944);         //   524288 B

    prep_all<<<dim3(24576), 256, 0, stream>>>(zr, zi, qwr, qwi, kwr, kwi, vwr, vwi,
                                              owr, owi, Zhi, Bqh, Boh);
    gemm_qkv<<<dim3(1536), 256, 0, stream>>>(Zhi, Bqh, QKhi, Vtr, Vti);
    attn_split<<<dim3(2048), 256, 0, stream>>>(QKhi, Vtr, Vti, Opart, Lp);
    combine<<<dim3(4096), 256, 0, stream>>>((const unsigned short*)Opart, Lp, aout);
    gemm_out<<<dim3(16, 32, 1), 256, 0, stream>>>(aout, Boh, (float*)d_out);
}